// Round 1
// baseline (13311.630 us; speedup 1.0000x reference)
//
#include <hip/hip_runtime.h>
#include <hip/hip_bf16.h>
#include <math.h>

#define S_LEN 4096
#define L_LEN 4095
#define DIN   1536
#define DM    768
#define NHEAD 12
#define HDIM  64
#define FFND  3072
#define NEGV  (-1e9f)
#define EPS   1e-5f

// ---------------------------------------------------------------- reductions
__device__ __forceinline__ float block_reduce_sum(float v, float* sbuf) {
#pragma unroll
    for (int o = 32; o > 0; o >>= 1) v += __shfl_down(v, o, 64);
    __syncthreads();
    if ((threadIdx.x & 63) == 0) sbuf[threadIdx.x >> 6] = v;
    __syncthreads();
    return sbuf[0] + sbuf[1] + sbuf[2] + sbuf[3];
}

__device__ __forceinline__ float gelu_tanh(float x) {
    float x3 = x * x * x;
    return 0.5f * x * (1.f + tanhf(0.7978845608f * (x + 0.044715f * x3)));
}

// ---------------------------------------------------------------- GEMM
// C[M,N] = f((A[M,K] @ B[K,N] + bias)*scale) [+ res];  BN = 128, BK = 16,
// BM = 64*MT.  256 threads, each computes (4*MT) x 8.
template <int MT>
__device__ __forceinline__ void gemm_body(
    const float* __restrict__ A, const float* __restrict__ B,
    const float* __restrict__ bias, const float* __restrict__ res,
    float* __restrict__ C, int M, int N, int K, float scale, int dogelu,
    int bx, int by)
{
    constexpr int BM = 64 * MT;
    __shared__ float As[16][BM];
    __shared__ float Bs[16][128];
    const int tid = threadIdx.x;
    const int bm = by * BM;
    const int bn = bx * 128;
    const int ty = tid >> 4;  // 0..15
    const int tx = tid & 15;  // 0..15

    float acc[4 * MT][8];
#pragma unroll
    for (int i = 0; i < 4 * MT; ++i)
#pragma unroll
        for (int j = 0; j < 8; ++j) acc[i][j] = 0.f;

    // B staging layout: row = tid>>4 (0..15), col = (tid&15)*8, two float4
    const int brow = tid >> 4;
    const int bcol = (tid & 15) * 8;

    for (int k0 = 0; k0 < K; k0 += 16) {
        float4 a0, a1;
        int arow, acol;
        if constexpr (MT == 2) {
            arow = tid >> 1; acol = (tid & 1) * 8;
            if (bm + arow < M) {
                const float* ap = &A[(size_t)(bm + arow) * K + k0 + acol];
                a0 = *(const float4*)ap; a1 = *(const float4*)(ap + 4);
            } else { a0 = make_float4(0, 0, 0, 0); a1 = a0; }
        } else {
            arow = tid >> 2; acol = (tid & 3) * 4;
            if (bm + arow < M) {
                a0 = *(const float4*)&A[(size_t)(bm + arow) * K + k0 + acol];
            } else { a0 = make_float4(0, 0, 0, 0); }
            a1 = make_float4(0, 0, 0, 0);
        }
        const float* bp = &B[(size_t)(k0 + brow) * N + bn + bcol];
        float4 b0 = *(const float4*)bp;
        float4 b1 = *(const float4*)(bp + 4);

        __syncthreads();  // protect previous iteration's reads
        As[acol + 0][arow] = a0.x; As[acol + 1][arow] = a0.y;
        As[acol + 2][arow] = a0.z; As[acol + 3][arow] = a0.w;
        if constexpr (MT == 2) {
            As[acol + 4][arow] = a1.x; As[acol + 5][arow] = a1.y;
            As[acol + 6][arow] = a1.z; As[acol + 7][arow] = a1.w;
        }
        *(float4*)&Bs[brow][bcol] = b0;
        *(float4*)&Bs[brow][bcol + 4] = b1;
        __syncthreads();

#pragma unroll
        for (int kk = 0; kk < 16; ++kk) {
            float a[4 * MT], b[8];
#pragma unroll
            for (int ii = 0; ii < MT; ++ii) {
                float4 t4 = *(const float4*)&As[kk][ty * 4 + ii * 64];
                a[ii * 4 + 0] = t4.x; a[ii * 4 + 1] = t4.y;
                a[ii * 4 + 2] = t4.z; a[ii * 4 + 3] = t4.w;
            }
            float4 bb0 = *(const float4*)&Bs[kk][tx * 4];
            float4 bb1 = *(const float4*)&Bs[kk][tx * 4 + 64];
            b[0] = bb0.x; b[1] = bb0.y; b[2] = bb0.z; b[3] = bb0.w;
            b[4] = bb1.x; b[5] = bb1.y; b[6] = bb1.z; b[7] = bb1.w;
#pragma unroll
            for (int i = 0; i < 4 * MT; ++i)
#pragma unroll
                for (int j = 0; j < 8; ++j) acc[i][j] += a[i] * b[j];
        }
    }

    // epilogue
#pragma unroll
    for (int ii = 0; ii < MT; ++ii) {
#pragma unroll
        for (int rr = 0; rr < 4; ++rr) {
            int row = bm + ty * 4 + ii * 64 + rr;
            if (row >= M) continue;
#pragma unroll
            for (int jj = 0; jj < 2; ++jj) {
                int col = bn + tx * 4 + jj * 64;
                float4 bsv = *(const float4*)&bias[col];
                float vx[4];
#pragma unroll
                for (int cc = 0; cc < 4; ++cc) {
                    float v = (acc[ii * 4 + rr][jj * 4 + cc] +
                               ((const float*)&bsv)[cc]) * scale;
                    if (dogelu) v = gelu_tanh(v);
                    vx[cc] = v;
                }
                float4 o;
                if (res) {
                    float4 rv = *(const float4*)&res[(size_t)row * N + col];
                    o = make_float4(vx[0] + rv.x, vx[1] + rv.y,
                                    vx[2] + rv.z, vx[3] + rv.w);
                } else {
                    o = make_float4(vx[0], vx[1], vx[2], vx[3]);
                }
                *(float4*)&C[(size_t)row * N + col] = o;
            }
        }
    }
}

__global__ __launch_bounds__(256) void gemm_mt1(
    const float* __restrict__ A, const float* __restrict__ B,
    const float* __restrict__ bias, const float* __restrict__ res,
    float* __restrict__ C, int M, int N, int K, float scale, int dogelu)
{
    gemm_body<1>(A, B, bias, res, C, M, N, K, scale, dogelu,
                 blockIdx.x, blockIdx.y);
}

__global__ __launch_bounds__(256) void gemm_mt2(
    const float* __restrict__ A, const float* __restrict__ B,
    const float* __restrict__ bias, const float* __restrict__ res,
    float* __restrict__ C, int M, int N, int K, float scale, int dogelu)
{
    gemm_body<2>(A, B, bias, res, C, M, N, K, scale, dogelu,
                 blockIdx.x, blockIdx.y);
}

// fused Q/K/V projection: blockIdx.z selects which output
__global__ __launch_bounds__(256) void qkv_gemm(
    const float* __restrict__ t,
    const float* __restrict__ wq, const float* __restrict__ wk,
    const float* __restrict__ wv,
    const float* __restrict__ bq, const float* __restrict__ bk,
    const float* __restrict__ bv,
    float* __restrict__ q, float* __restrict__ k, float* __restrict__ v)
{
    int z = blockIdx.z;
    const float* B = (z == 0) ? wq : (z == 1) ? wk : wv;
    const float* bias = (z == 0) ? bq : (z == 1) ? bk : bv;
    float* C = (z == 0) ? q : (z == 1) ? k : v;
    float scale = (z == 0) ? 0.125f : 1.0f;  // HD^-0.5 = 1/8
    gemm_body<1>(t, B, bias, nullptr, C, S_LEN, DM, DM, scale, 0,
                 blockIdx.x, blockIdx.y);
}

// ---------------------------------------------------------------- LayerNorm
__global__ __launch_bounds__(256) void ln_kernel(
    const float* __restrict__ in, float* __restrict__ out,
    const float* __restrict__ g, const float* __restrict__ b)
{
    __shared__ float sbuf[4];
    const int s = blockIdx.x;
    const int tid = threadIdx.x;
    const float* row = in + (size_t)s * DM;
    float x0 = row[tid], x1 = row[tid + 256], x2 = row[tid + 512];
    float m = block_reduce_sum(x0 + x1 + x2, sbuf) * (1.f / DM);
    float d0 = x0 - m, d1 = x1 - m, d2 = x2 - m;
    float var = block_reduce_sum(d0 * d0 + d1 * d1 + d2 * d2, sbuf) * (1.f / DM);
    float rs = rsqrtf(var + EPS);
    float* orow = out + (size_t)s * DM;
    orow[tid]       = d0 * rs * g[tid]       + b[tid];
    orow[tid + 256] = d1 * rs * g[tid + 256] + b[tid + 256];
    orow[tid + 512] = d2 * rs * g[tid + 512] + b[tid + 512];
}

// ------------------------------------------------- pos-embed add + cls row
__global__ __launch_bounds__(256) void posadd_kernel(
    float* __restrict__ h, const float* __restrict__ coords,
    const float* __restrict__ pe, const float* __restrict__ cls)
{
    const int s = blockIdx.x;
    const int tid = threadIdx.x;
    if (s == 0) {
        for (int c = tid; c < DM; c += 256) h[c] = cls[c] + pe[c];
    } else {
        float c0 = floorf(coords[(size_t)(s - 1) * 2 + 0] * (1.f / 256.f));
        float c1 = floorf(coords[(size_t)(s - 1) * 2 + 1] * (1.f / 256.f));
        int pos = (int)(c0 * 128.f + c1) + 1;
        float* hr = h + (size_t)s * DM;
        const float* pr = pe + (size_t)pos * DM;
        for (int c = tid; c < DM; c += 256) hr[c] += pr[c];
    }
}

// ---------------------------------------------------------------- attention
__global__ __launch_bounds__(256) void init_acc_kernel(
    float* __restrict__ accO, float* __restrict__ accM, float* __restrict__ accD)
{
    size_t i = (size_t)blockIdx.x * 256 + threadIdx.x;
    accO[i] = 0.f;  // grid sized exactly S*D/256
    if (i < (size_t)S_LEN * NHEAD) { accM[i] = NEGV; accD[i] = 0.f; }
}

// One block = (seg, head, 256-query chunk). 1 thread per query row.
// Online softmax over valid keys; then online logsumexp-merge into the
// cross-branch accumulator (unique writer per (s,head) per branch).
__global__ __launch_bounds__(256) void branch_attn_kernel(
    const float* __restrict__ q, const float* __restrict__ k,
    const float* __restrict__ v,
    float* __restrict__ accO, float* __restrict__ accM,
    float* __restrict__ accD, int w, int r)
{
    __shared__ float Ks[64][64];
    __shared__ float Vs[64][64];
    const int tid = threadIdx.x;
    const int bid = blockIdx.x;
    const int qc = bid & 3;
    const int hh = (bid >> 2) % NHEAD;
    const int seg = bid / (4 * NHEAD);
    const int off = hh & (r - 1);
    const int jq = qc * 256 + tid;
    const long sq = (long)seg * w + off + (long)r * jq;
    int nvalid = (S_LEN - seg * w - off + r - 1) / r;
    if (nvalid > 1024) nvalid = 1024;
    const bool active = (sq < S_LEN);

    float4 q4[16];
    if (active) {
        const float4* qrow = (const float4*)(q + ((size_t)sq * NHEAD + hh) * HDIM);
#pragma unroll
        for (int d = 0; d < 16; ++d) q4[d] = qrow[d];
    }
    float rm = -INFINITY, rd = 0.f;
    float4 o4[16];
#pragma unroll
    for (int d = 0; d < 16; ++d) o4[d] = make_float4(0, 0, 0, 0);

    const size_t base = (size_t)seg * w + off;
    for (int kt = 0; kt < nvalid; kt += 64) {
        const int nk = min(64, nvalid - kt);
        __syncthreads();
        for (int i = tid; i < 64 * 16; i += 256) {
            int kr = i >> 4, kd = i & 15;
            float4 kv = make_float4(0, 0, 0, 0), vv = make_float4(0, 0, 0, 0);
            if (kr < nk) {
                size_t sk = base + (size_t)r * (kt + kr);
                const float4* kp = (const float4*)(k + (sk * NHEAD + hh) * HDIM);
                const float4* vp = (const float4*)(v + (sk * NHEAD + hh) * HDIM);
                kv = kp[kd]; vv = vp[kd];
            }
            *(float4*)&Ks[kr][kd * 4] = kv;
            *(float4*)&Vs[kr][kd * 4] = vv;
        }
        __syncthreads();
        if (active) {
            for (int kk = 0; kk < nk; ++kk) {
                const float4* kr4 = (const float4*)Ks[kk];
                float s0 = 0, s1 = 0, s2 = 0, s3 = 0;
#pragma unroll
                for (int d = 0; d < 16; d += 4) {
                    float4 ka = kr4[d], kb = kr4[d + 1], kc = kr4[d + 2], kd4 = kr4[d + 3];
                    s0 += q4[d].x * ka.x + q4[d].y * ka.y + q4[d].z * ka.z + q4[d].w * ka.w;
                    s1 += q4[d + 1].x * kb.x + q4[d + 1].y * kb.y + q4[d + 1].z * kb.z + q4[d + 1].w * kb.w;
                    s2 += q4[d + 2].x * kc.x + q4[d + 2].y * kc.y + q4[d + 2].z * kc.z + q4[d + 2].w * kc.w;
                    s3 += q4[d + 3].x * kd4.x + q4[d + 3].y * kd4.y + q4[d + 3].z * kd4.z + q4[d + 3].w * kd4.w;
                }
                float sc = (s0 + s1) + (s2 + s3);
                float p;
                if (sc <= rm) {
                    p = __expf(sc - rm);
                } else {
                    float alpha = __expf(rm - sc);
                    rd *= alpha;
#pragma unroll
                    for (int d = 0; d < 16; ++d) {
                        o4[d].x *= alpha; o4[d].y *= alpha;
                        o4[d].z *= alpha; o4[d].w *= alpha;
                    }
                    rm = sc;
                    p = 1.f;
                }
                rd += p;
                const float4* vr4 = (const float4*)Vs[kk];
#pragma unroll
                for (int d = 0; d < 16; ++d) {
                    float4 vv = vr4[d];
                    o4[d].x += p * vv.x; o4[d].y += p * vv.y;
                    o4[d].z += p * vv.z; o4[d].w += p * vv.w;
                }
            }
        }
    }
    if (active) {
        float lse = rm + __logf(rd);
        size_t idx = (size_t)sq * NHEAD + hh;
        float mprev = accM[idx];
        float dprev = accD[idx];
        float nm = fmaxf(mprev, lse);
        float a0 = __expf(mprev - nm);
        float a1 = __expf(lse - nm);
        accM[idx] = nm;
        accD[idx] = dprev * a0 + a1;
        float* arow = accO + idx * HDIM;
        float inv = 1.f / rd;
#pragma unroll
        for (int d = 0; d < 16; ++d) {
            float4 cur = *(float4*)&arow[d * 4];
            cur.x = cur.x * a0 + a1 * (o4[d].x * inv);
            cur.y = cur.y * a0 + a1 * (o4[d].y * inv);
            cur.z = cur.z * a0 + a1 * (o4[d].z * inv);
            cur.w = cur.w * a0 + a1 * (o4[d].w * inv);
            *(float4*)&arow[d * 4] = cur;
        }
    }
}

__global__ __launch_bounds__(256) void attn_final_kernel(
    const float* __restrict__ accO, const float* __restrict__ accD,
    float* __restrict__ out)
{
    const int s = blockIdx.x;
    const int tid = threadIdx.x;
    for (int c = tid; c < DM; c += 256) {
        out[(size_t)s * DM + c] =
            accO[(size_t)s * DM + c] / accD[s * NHEAD + (c >> 6)];
    }
}

// ---------------------------------------------------- final double-LN, row 0
__global__ __launch_bounds__(256) void final_ln_kernel(
    const float* __restrict__ h,
    const float* __restrict__ g1, const float* __restrict__ b1,
    const float* __restrict__ g2, const float* __restrict__ b2,
    float* __restrict__ out)
{
    __shared__ float sbuf[4];
    const int tid = threadIdx.x;
    float x0 = h[tid], x1 = h[tid + 256], x2 = h[tid + 512];
    float m = block_reduce_sum(x0 + x1 + x2, sbuf) * (1.f / DM);
    float d0 = x0 - m, d1 = x1 - m, d2 = x2 - m;
    float var = block_reduce_sum(d0 * d0 + d1 * d1 + d2 * d2, sbuf) * (1.f / DM);
    float rs = rsqrtf(var + EPS);
    float y0 = d0 * rs * g1[tid]       + b1[tid];
    float y1 = d1 * rs * g1[tid + 256] + b1[tid + 256];
    float y2 = d2 * rs * g1[tid + 512] + b1[tid + 512];
    m = block_reduce_sum(y0 + y1 + y2, sbuf) * (1.f / DM);
    d0 = y0 - m; d1 = y1 - m; d2 = y2 - m;
    var = block_reduce_sum(d0 * d0 + d1 * d1 + d2 * d2, sbuf) * (1.f / DM);
    rs = rsqrtf(var + EPS);
    out[tid]       = d0 * rs * g2[tid]       + b2[tid];
    out[tid + 256] = d1 * rs * g2[tid + 256] + b2[tid + 256];
    out[tid + 512] = d2 * rs * g2[tid + 512] + b2[tid + 512];
}

// ---------------------------------------------------------------- launcher
extern "C" void kernel_launch(void* const* d_in, const int* in_sizes, int n_in,
                              void* d_out, int out_size, void* d_ws, size_t ws_size,
                              hipStream_t stream)
{
    (void)in_sizes; (void)n_in; (void)out_size; (void)ws_size;
    const float* x        = (const float*)d_in[0];
    const float* coords   = (const float*)d_in[1];
    const float* pos_emb  = (const float*)d_in[2];
    const float* cls_tok  = (const float*)d_in[3];
    const float* patch_w  = (const float*)d_in[4];
    const float* patch_b  = (const float*)d_in[5];
    const float* ln1_g    = (const float*)d_in[6];
    const float* ln1_b    = (const float*)d_in[7];
    const float* wq       = (const float*)d_in[8];
    const float* bq       = (const float*)d_in[9];
    const float* wk       = (const float*)d_in[10];
    const float* bk       = (const float*)d_in[11];
    const float* wv       = (const float*)d_in[12];
    const float* bv       = (const float*)d_in[13];
    const float* wo       = (const float*)d_in[14];
    const float* bo       = (const float*)d_in[15];
    const float* ln2_g    = (const float*)d_in[16];
    const float* ln2_b    = (const float*)d_in[17];
    const float* w1       = (const float*)d_in[18];
    const float* b1       = (const float*)d_in[19];
    const float* w2       = (const float*)d_in[20];
    const float* b2       = (const float*)d_in[21];
    const float* enc_g    = (const float*)d_in[22];
    const float* enc_b    = (const float*)d_in[23];
    const float* norm_g   = (const float*)d_in[24];
    const float* norm_b   = (const float*)d_in[25];
    float* out = (float*)d_out;

    float* ws = (float*)d_ws;
    const size_t SD = (size_t)S_LEN * DM;
    float* h    = ws;
    float* t    = h + SD;
    float* q    = t + SD;
    float* kbuf = q + SD;
    float* vbuf = kbuf + SD;
    float* accO = vbuf + SD;
    float* accM = accO + SD;
    float* accD = accM + (size_t)S_LEN * NHEAD;
    float* ffn  = q;  // aliases q,k,v,accO (4*SD) — all dead during FFN

    // patch embed: h rows 1..4095  (C base offset by one row)
    gemm_mt1<<<dim3(DM / 128, (L_LEN + 63) / 64), 256, 0, stream>>>(
        x, patch_w, patch_b, nullptr, h + DM, L_LEN, DM, DIN, 1.f, 0);
    posadd_kernel<<<S_LEN, 256, 0, stream>>>(h, coords, pos_emb, cls_tok);

    const int BR_W[5] = {1024, 2048, 4096, 8192, 16384};
    const int BR_R[5] = {1, 2, 4, 8, 16};
    const int BR_N[5] = {4, 2, 1, 1, 1};

    for (int l = 0; l < 4; ++l) {
        const size_t lDD = (size_t)l * DM * DM;
        ln_kernel<<<S_LEN, 256, 0, stream>>>(h, t, ln1_g + l * DM, ln1_b + l * DM);
        qkv_gemm<<<dim3(DM / 128, S_LEN / 64, 3), 256, 0, stream>>>(
            t, wq + lDD, wk + lDD, wv + lDD,
            bq + l * DM, bk + l * DM, bv + l * DM, q, kbuf, vbuf);
        init_acc_kernel<<<(int)(SD / 256), 256, 0, stream>>>(accO, accM, accD);
        for (int b = 0; b < 5; ++b) {
            branch_attn_kernel<<<BR_N[b] * NHEAD * 4, 256, 0, stream>>>(
                q, kbuf, vbuf, accO, accM, accD, BR_W[b], BR_R[b]);
        }
        attn_final_kernel<<<S_LEN, 256, 0, stream>>>(accO, accD, t);
        gemm_mt1<<<dim3(DM / 128, S_LEN / 64), 256, 0, stream>>>(
            t, wo + lDD, bo + l * DM, h, h, S_LEN, DM, DM, 1.f, 0);
        ln_kernel<<<S_LEN, 256, 0, stream>>>(h, t, ln2_g + l * DM, ln2_b + l * DM);
        gemm_mt2<<<dim3(FFND / 128, S_LEN / 128), 256, 0, stream>>>(
            t, w1 + (size_t)l * DM * FFND, b1 + (size_t)l * FFND, nullptr, ffn,
            S_LEN, FFND, DM, 1.f, 1);
        gemm_mt1<<<dim3(DM / 128, S_LEN / 64), 256, 0, stream>>>(
            ffn, w2 + (size_t)l * FFND * DM, b2 + l * DM, h, h,
            S_LEN, DM, FFND, 1.f, 0);
    }
    final_ln_kernel<<<1, 256, 0, stream>>>(h, enc_g, enc_b, norm_g, norm_b, out);
}

// Round 2
// 1368.638 us; speedup vs baseline: 9.7262x; 9.7262x over previous
//
#include <hip/hip_runtime.h>
#include <hip/hip_bf16.h>
#include <math.h>
#include <stdint.h>

#define S_LEN 4096
#define L_LEN 4095
#define DIN   1536
#define DM    768
#define NHEAD 12
#define HDIM  64
#define FFND  3072
#define NEGV  (-1e9f)
#define EPS   1e-5f

typedef unsigned short u16;
typedef unsigned int   u32;
typedef short short8 __attribute__((ext_vector_type(8)));
typedef float f32x4 __attribute__((ext_vector_type(4)));

// ---------------------------------------------------------------- helpers
__device__ __forceinline__ u16 f2b(float f) {
    union { float f; u32 u; } x; x.f = f;
    u32 r = (x.u + 0x7FFF + ((x.u >> 16) & 1)) >> 16;
    return (u16)r;
}
__device__ __forceinline__ float b2f(u16 v) {
    union { u32 u; float f; } x; x.u = ((u32)v) << 16;
    return x.f;
}
__device__ __forceinline__ float gelu_tanh(float x) {
    float x3 = x * x * x;
    return 0.5f * x * (1.f + tanhf(0.7978845608f * (x + 0.044715f * x3)));
}
__device__ __forceinline__ float block_reduce_sum(float v, float* sbuf) {
#pragma unroll
    for (int o = 32; o > 0; o >>= 1) v += __shfl_down(v, o, 64);
    __syncthreads();
    if ((threadIdx.x & 63) == 0) sbuf[threadIdx.x >> 6] = v;
    __syncthreads();
    return sbuf[0] + sbuf[1] + sbuf[2] + sbuf[3];
}
__device__ __forceinline__ void gload16(const void* g, void* l) {
    __builtin_amdgcn_global_load_lds((const __attribute__((address_space(1))) void*)g,
                                     (__attribute__((address_space(3))) void*)l,
                                     16, 0, 0);
}

// ---------------------------------------------------------------- GEMM (bf16 MFMA, B^T layout)
// A[M][K] bf16 row-major, Bt[N][K] bf16 row-major.  Tile 128 x BN, BK=64.
// 256 threads = 4 waves (2x2 wave grid).  out = f((A@B + bias)*scale) [+ res]
template <int BN>
__device__ __forceinline__ void gemm_bt(
    const u16* __restrict__ A, const u16* __restrict__ Bt,
    const float* __restrict__ bias, const float* __restrict__ res,
    float* __restrict__ outf, u16* __restrict__ outb,
    int M, int N, int K, float scale, int dogelu, int bx, int by)
{
    constexpr int NI = BN / 32;   // acc tiles along N per wave
    constexpr int BI = BN / 32;   // gload iters per wave for B
    __shared__ u16 As[128 * 64];
    __shared__ u16 Bs[BN * 64];
    const int tid = threadIdx.x, wv = tid >> 6, l = tid & 63;
    const int bm = by * 128, bn = bx * BN;
    const int wm = wv >> 1, wn = wv & 1;

    f32x4 acc[4][NI];
#pragma unroll
    for (int i = 0; i < 4; ++i)
#pragma unroll
        for (int j = 0; j < NI; ++j) acc[i][j] = (f32x4){0.f, 0.f, 0.f, 0.f};

    for (int k0 = 0; k0 < K; k0 += 64) {
        // stage A (pre-swizzled source so linear LDS dest + swizzled reads match)
#pragma unroll
        for (int i = 0; i < 4; ++i) {
            int row = (wv * 4 + i) * 8 + (l >> 3);
            int col = ((l & 7) ^ (row & 7)) * 8;
            int grow = bm + row; if (grow > M - 1) grow = M - 1;
            gload16(A + (size_t)grow * K + k0 + col, &As[(wv * 4 + i) * 512]);
        }
#pragma unroll
        for (int i = 0; i < BI; ++i) {
            int row = (wv * BI + i) * 8 + (l >> 3);
            int col = ((l & 7) ^ (row & 7)) * 8;
            gload16(Bt + (size_t)(bn + row) * K + k0 + col, &Bs[(wv * BI + i) * 512]);
        }
        __syncthreads();
#pragma unroll
        for (int kc = 0; kc < 2; ++kc) {
            short8 a[4], b[NI];
#pragma unroll
            for (int mi = 0; mi < 4; ++mi) {
                int row = wm * 64 + mi * 16 + (l & 15);
                int off = ((l >> 4) * 16 + kc * 64) ^ ((row & 7) << 4);
                a[mi] = *(const short8*)&As[(row * 128 + off) >> 1];
            }
#pragma unroll
            for (int ni = 0; ni < NI; ++ni) {
                int row = wn * (BN / 2) + ni * 16 + (l & 15);
                int off = ((l >> 4) * 16 + kc * 64) ^ ((row & 7) << 4);
                b[ni] = *(const short8*)&Bs[(row * 128 + off) >> 1];
            }
#pragma unroll
            for (int mi = 0; mi < 4; ++mi)
#pragma unroll
                for (int ni = 0; ni < NI; ++ni)
                    acc[mi][ni] = __builtin_amdgcn_mfma_f32_16x16x32_bf16(
                        a[mi], b[ni], acc[mi][ni], 0, 0, 0);
        }
        __syncthreads();
    }
    // epilogue: C/D layout col = l&15, row = (l>>4)*4 + reg
#pragma unroll
    for (int mi = 0; mi < 4; ++mi) {
#pragma unroll
        for (int rg = 0; rg < 4; ++rg) {
            int row = bm + wm * 64 + mi * 16 + (l >> 4) * 4 + rg;
            if (row >= M) continue;
#pragma unroll
            for (int ni = 0; ni < NI; ++ni) {
                int col = bn + wn * (BN / 2) + ni * 16 + (l & 15);
                float v = (acc[mi][ni][rg] + bias[col]) * scale;
                if (dogelu) v = gelu_tanh(v);
                if (res) v += res[(size_t)row * N + col];
                if (outf) outf[(size_t)row * N + col] = v;
                if (outb) outb[(size_t)row * N + col] = f2b(v);
            }
        }
    }
}

__global__ __launch_bounds__(256) void gemm128_kernel(
    const u16* __restrict__ A, const u16* __restrict__ Bt,
    const float* __restrict__ bias, const float* __restrict__ res,
    float* __restrict__ outf, u16* __restrict__ outb,
    int M, int N, int K, float scale, int dogelu)
{
    gemm_bt<128>(A, Bt, bias, res, outf, outb, M, N, K, scale, dogelu,
                 blockIdx.x, blockIdx.y);
}
__global__ __launch_bounds__(256) void gemm64_kernel(
    const u16* __restrict__ A, const u16* __restrict__ Bt,
    const float* __restrict__ bias, const float* __restrict__ res,
    float* __restrict__ outf, u16* __restrict__ outb,
    int M, int N, int K, float scale, int dogelu)
{
    gemm_bt<64>(A, Bt, bias, res, outf, outb, M, N, K, scale, dogelu,
                blockIdx.x, blockIdx.y);
}
__global__ __launch_bounds__(256) void qkv_kernel(
    const u16* __restrict__ t,
    const u16* __restrict__ wqT, const u16* __restrict__ wkT, const u16* __restrict__ wvT,
    const float* __restrict__ bq, const float* __restrict__ bk, const float* __restrict__ bv,
    u16* __restrict__ q, u16* __restrict__ k, u16* __restrict__ v)
{
    int z = blockIdx.z;
    const u16* B = (z == 0) ? wqT : (z == 1) ? wkT : wvT;
    const float* bias = (z == 0) ? bq : (z == 1) ? bk : bv;
    u16* C = (z == 0) ? q : (z == 1) ? k : v;
    float scale = (z == 0) ? 0.125f : 1.0f;
    gemm_bt<128>(t, B, bias, nullptr, nullptr, C, S_LEN, DM, DM, scale, 0,
                 blockIdx.x, blockIdx.y);
}

// ---------------------------------------------------------- transpose+convert
// src f32 [K][N] -> dst bf16 [N][K];  z selects among 4 sources, dst strided.
__global__ __launch_bounds__(256) void transpose_cvt(
    const float* __restrict__ s0, const float* __restrict__ s1,
    const float* __restrict__ s2, const float* __restrict__ s3,
    u16* __restrict__ dst, int K, int N)
{
    int z = blockIdx.z;
    const float* src = (z == 0) ? s0 : (z == 1) ? s1 : (z == 2) ? s2 : s3;
    u16* d = dst + (size_t)z * K * N;
    __shared__ float tile[64][65];
    const int t = threadIdx.x;
    const int tk = blockIdx.y * 64, tn = blockIdx.x * 64;
    const int r0 = t >> 4, c0 = (t & 15) * 4;
#pragma unroll
    for (int i = 0; i < 4; ++i) {
        const float* sp = &src[(size_t)(tk + r0 + i * 16) * N + tn + c0];
        tile[r0 + i * 16][c0 + 0] = sp[0];
        tile[r0 + i * 16][c0 + 1] = sp[1];
        tile[r0 + i * 16][c0 + 2] = sp[2];
        tile[r0 + i * 16][c0 + 3] = sp[3];
    }
    __syncthreads();
#pragma unroll
    for (int i = 0; i < 4; ++i) {
        int nr = r0 + i * 16;
        u32 lo = (u32)f2b(tile[c0 + 0][nr]) | ((u32)f2b(tile[c0 + 1][nr]) << 16);
        u32 hi = (u32)f2b(tile[c0 + 2][nr]) | ((u32)f2b(tile[c0 + 3][nr]) << 16);
        *(uint2*)&d[(size_t)(tn + nr) * K + tk + c0] = make_uint2(lo, hi);
    }
}

__global__ __launch_bounds__(256) void cvt_bf16_kernel(
    const float* __restrict__ x, u16* __restrict__ xb, int n4)
{
    int stride = gridDim.x * 256;
    for (int i = blockIdx.x * 256 + threadIdx.x; i < n4; i += stride) {
        float4 v = ((const float4*)x)[i];
        u32 lo = (u32)f2b(v.x) | ((u32)f2b(v.y) << 16);
        u32 hi = (u32)f2b(v.z) | ((u32)f2b(v.w) << 16);
        ((uint2*)xb)[i] = make_uint2(lo, hi);
    }
}

// ---------------------------------------------------------------- LayerNorm (f32 in -> bf16 out)
__global__ __launch_bounds__(256) void ln_kernel(
    const float* __restrict__ in, u16* __restrict__ out,
    const float* __restrict__ g, const float* __restrict__ b)
{
    __shared__ float sbuf[4];
    const int s = blockIdx.x;
    const int tid = threadIdx.x;
    const float* row = in + (size_t)s * DM;
    float x0 = row[tid], x1 = row[tid + 256], x2 = row[tid + 512];
    float m = block_reduce_sum(x0 + x1 + x2, sbuf) * (1.f / DM);
    float d0 = x0 - m, d1 = x1 - m, d2 = x2 - m;
    float var = block_reduce_sum(d0 * d0 + d1 * d1 + d2 * d2, sbuf) * (1.f / DM);
    float rs = rsqrtf(var + EPS);
    u16* orow = out + (size_t)s * DM;
    orow[tid]       = f2b(d0 * rs * g[tid]       + b[tid]);
    orow[tid + 256] = f2b(d1 * rs * g[tid + 256] + b[tid + 256]);
    orow[tid + 512] = f2b(d2 * rs * g[tid + 512] + b[tid + 512]);
}

// ------------------------------------------------- pos-embed add + cls row (f32 h)
__global__ __launch_bounds__(256) void posadd_kernel(
    float* __restrict__ h, const float* __restrict__ coords,
    const float* __restrict__ pe, const float* __restrict__ cls)
{
    const int s = blockIdx.x;
    const int tid = threadIdx.x;
    if (s == 0) {
        for (int c = tid; c < DM; c += 256) h[c] = cls[c] + pe[c];
    } else {
        float c0 = floorf(coords[(size_t)(s - 1) * 2 + 0] * (1.f / 256.f));
        float c1 = floorf(coords[(size_t)(s - 1) * 2 + 1] * (1.f / 256.f));
        int pos = (int)(c0 * 128.f + c1) + 1;
        float* hr = h + (size_t)s * DM;
        const float* pr = pe + (size_t)pos * DM;
        for (int c = tid; c < DM; c += 256) hr[c] += pr[c];
    }
}

// ---------------------------------------------------------------- attention
__global__ __launch_bounds__(256) void lse_init_kernel(float* __restrict__ lse)
{
    lse[(size_t)blockIdx.x * 256 + threadIdx.x] = NEGV;
}

// One block = (branch, seg, head, 64-query tile).  4 waves x 16 queries.
// MFMA 16x16x32 bf16 for QK^T and PV; per-branch (o,lse) outputs.
__global__ __launch_bounds__(256) void attn_kernel(
    const u16* __restrict__ qb, const u16* __restrict__ kb, const u16* __restrict__ vb,
    u16* __restrict__ obuf, float* __restrict__ lse)
{
    __shared__ u16 Ks[64 * 64];       // [key][hd] swizzled
    __shared__ u16 Vt[64 * 64];       // [hd][key] swizzled (transposed)
    __shared__ u16 Pt[4 * 16 * 64];   // per-wave [q16][key64] swizzled

    const int tid = threadIdx.x, wv = tid >> 6, l = tid & 63;
    const int bid = blockIdx.x;
    int b, rem;
    if (bid < 768)       { b = 0; rem = bid; }
    else if (bid < 1152) { b = 1; rem = bid - 768; }
    else if (bid < 1344) { b = 2; rem = bid - 1152; }
    else if (bid < 1440) { b = 3; rem = bid - 1344; }
    else                 { b = 4; rem = bid - 1440; }
    const int r = 1 << b;
    const int w = 1024 << b;
    const int qt = (b < 3) ? 16 : (b == 3 ? 8 : 4);
    const int nv = (b < 3) ? 1024 : (b == 3 ? 512 : 256);
    const int qtile = rem % qt; rem /= qt;
    const int head = rem % NHEAD;
    const int seg = rem / NHEAD;
    const int off = head & (r - 1);
    const size_t base = (size_t)seg * w + off;

    // Q fragments (A layout: row = l&15, k = (l>>4)*8 + j), hd chunks kc=0,1
    const int jql = qtile * 64 + wv * 16 + (l & 15);
    const size_t sqf = base + (size_t)r * jql;
    const u16* qp = qb + sqf * DM + head * 64 + (l >> 4) * 8;
    short8 qf0 = *(const short8*)qp;
    short8 qf1 = *(const short8*)(qp + 32);

    f32x4 acc[4];
#pragma unroll
    for (int hg = 0; hg < 4; ++hg) acc[hg] = (f32x4){0.f, 0.f, 0.f, 0.f};
    float m0 = -INFINITY, m1 = -INFINITY, m2 = -INFINITY, m3 = -INFINITY;
    float dd0 = 0.f, dd1 = 0.f, dd2 = 0.f, dd3 = 0.f;

    const int pbase = wv * 1024;  // u16 units

    for (int kt = 0; kt < nv; kt += 64) {
        if (kt) __syncthreads();
        // ---- stage K tile [64key][64hd], swizzled 16B chunks
        {
            int kr = tid >> 2;
            int cb = (tid & 3) * 32;
            size_t krow = base + (size_t)r * (kt + kr);
            const u16* kp = kb + krow * DM + head * 64;
            short8 kv0 = *(const short8*)(kp + (cb >> 1));
            short8 kv1 = *(const short8*)(kp + (cb >> 1) + 8);
            int sw = (kr & 7) << 4;
            *(short8*)&Ks[(kr * 128 + (cb ^ sw)) >> 1] = kv0;
            *(short8*)&Ks[(kr * 128 + ((cb + 16) ^ sw)) >> 1] = kv1;
        }
        // ---- stage V^T tile [64hd][64key], packed u32 writes, rotated i
        {
            int c = tid & 7, p = tid >> 3;  // hd chunk, key pair
            size_t vr0 = base + (size_t)r * (kt + 2 * p);
            const u16* v0p = vb + vr0 * DM + head * 64 + c * 8;
            const u16* v1p = vb + (vr0 + r) * DM + head * 64 + c * 8;
            short8 va = *(const short8*)v0p;
            short8 vbv = *(const short8*)v1p;
#pragma unroll
            for (int j = 0; j < 8; ++j) {
                int i = (j + c) & 7;
                int hd = c * 8 + i;
                u32 val = (u32)(u16)va[i] | ((u32)(u16)vbv[i] << 16);
                int byte = (hd * 128) + ((p * 4) ^ (i << 4));
                *(u32*)&Vt[byte >> 1] = val;
            }
        }
        __syncthreads();

        // ---- QK^T: S[16q x 64key], D-layout rows=(l>>4)*4+rg, col=l&15 (+16*kg)
        f32x4 sv[4];
#pragma unroll
        for (int kg = 0; kg < 4; ++kg) {
            f32x4 sa = (f32x4){0.f, 0.f, 0.f, 0.f};
#pragma unroll
            for (int kc = 0; kc < 2; ++kc) {
                int row = kg * 16 + (l & 15);
                int offb = ((l >> 4) * 16 + kc * 64) ^ ((row & 7) << 4);
                short8 kf = *(const short8*)&Ks[(row * 128 + offb) >> 1];
                sa = __builtin_amdgcn_mfma_f32_16x16x32_bf16(
                    (kc == 0) ? qf0 : qf1, kf, sa, 0, 0, 0);
            }
            sv[kg] = sa;
        }

        // ---- online softmax (rows spread over 16-lane groups)
        float pw[4][4];
        float mcur[4] = {m0, m1, m2, m3};
        float dcur[4] = {dd0, dd1, dd2, dd3};
        float al[4];
#pragma unroll
        for (int rg = 0; rg < 4; ++rg) {
            float mx = fmaxf(fmaxf(sv[0][rg], sv[1][rg]), fmaxf(sv[2][rg], sv[3][rg]));
            mx = fmaxf(mx, __shfl_xor(mx, 1, 64));
            mx = fmaxf(mx, __shfl_xor(mx, 2, 64));
            mx = fmaxf(mx, __shfl_xor(mx, 4, 64));
            mx = fmaxf(mx, __shfl_xor(mx, 8, 64));
            float nm = fmaxf(mcur[rg], mx);
            al[rg] = __expf(mcur[rg] - nm);
            mcur[rg] = nm;
            float s = 0.f;
#pragma unroll
            for (int kg = 0; kg < 4; ++kg) {
                float pv = __expf(sv[kg][rg] - nm);
                pw[kg][rg] = pv;
                s += pv;
            }
            s += __shfl_xor(s, 1, 64);
            s += __shfl_xor(s, 2, 64);
            s += __shfl_xor(s, 4, 64);
            s += __shfl_xor(s, 8, 64);
            dcur[rg] = dcur[rg] * al[rg] + s;
        }
        m0 = mcur[0]; m1 = mcur[1]; m2 = mcur[2]; m3 = mcur[3];
        dd0 = dcur[0]; dd1 = dcur[1]; dd2 = dcur[2]; dd3 = dcur[3];
#pragma unroll
        for (int hg = 0; hg < 4; ++hg) {
            acc[hg][0] *= al[0]; acc[hg][1] *= al[1];
            acc[hg][2] *= al[2]; acc[hg][3] *= al[3];
        }

        // ---- P -> LDS (own wave region), bf16, swizzled
#pragma unroll
        for (int kg = 0; kg < 4; ++kg)
#pragma unroll
            for (int rg = 0; rg < 4; ++rg) {
                int qr = (l >> 4) * 4 + rg;
                int colb = ((l & 15) + kg * 16) * 2;
                int byte = qr * 128 + (colb ^ ((qr & 7) << 4));
                Pt[pbase + (byte >> 1)] = f2b(pw[kg][rg]);
            }

        // ---- PV: O[16q x 64hd] += P @ V
        short8 pa0, pa1;
        {
            int row = l & 15;
            int o0 = ((l >> 4) * 16) ^ ((row & 7) << 4);
            int o1 = ((l >> 4) * 16 + 64) ^ ((row & 7) << 4);
            pa0 = *(const short8*)&Pt[pbase + ((row * 128 + o0) >> 1)];
            pa1 = *(const short8*)&Pt[pbase + ((row * 128 + o1) >> 1)];
        }
#pragma unroll
        for (int hg = 0; hg < 4; ++hg) {
#pragma unroll
            for (int kc = 0; kc < 2; ++kc) {
                int row = hg * 16 + (l & 15);
                int offb = ((l >> 4) * 16 + kc * 64) ^ ((row & 7) << 4);
                short8 vf = *(const short8*)&Vt[(row * 128 + offb) >> 1];
                acc[hg] = __builtin_amdgcn_mfma_f32_16x16x32_bf16(
                    (kc == 0) ? pa0 : pa1, vf, acc[hg], 0, 0, 0);
            }
        }
    }

    // ---- epilogue: normalized O (bf16) + lse, per-branch buffers
    u16* ob = obuf + (size_t)b * S_LEN * DM;
    float* lse_b = lse + (size_t)b * S_LEN * NHEAD;
    float mv[4] = {m0, m1, m2, m3};
    float dv[4] = {dd0, dd1, dd2, dd3};
#pragma unroll
    for (int rg = 0; rg < 4; ++rg) {
        float invd = 1.0f / dv[rg];
        int jqr = qtile * 64 + wv * 16 + (l >> 4) * 4 + rg;
        size_t sq = base + (size_t)r * jqr;
        u16* orow = ob + sq * DM + head * 64;
#pragma unroll
        for (int hg = 0; hg < 4; ++hg)
            orow[hg * 16 + (l & 15)] = f2b(acc[hg][rg] * invd);
        if ((l & 15) == 0)
            lse_b[sq * NHEAD + head] = mv[rg] + __logf(dv[rg]);
    }
}

// ---- LongNet combine: t[s][c] = sum_b softmax_b(lse)[b] * o_b[s][c]
__global__ __launch_bounds__(256) void combine_kernel(
    const u16* __restrict__ obuf, const float* __restrict__ lse,
    u16* __restrict__ t)
{
    const int s = blockIdx.x;
    const int tid = threadIdx.x;
    const size_t SD = (size_t)S_LEN * DM;
#pragma unroll
    for (int j = 0; j < 3; ++j) {
        int c = tid + j * 256;
        int head = c >> 6;
        float lv[5];
#pragma unroll
        for (int b = 0; b < 5; ++b)
            lv[b] = lse[((size_t)b * S_LEN + s) * NHEAD + head];
        float mx = fmaxf(fmaxf(fmaxf(lv[0], lv[1]), fmaxf(lv[2], lv[3])), lv[4]);
        float wsum = 0.f, ov = 0.f;
#pragma unroll
        for (int b = 0; b < 5; ++b) {
            float wb = __expf(lv[b] - mx);
            wsum += wb;
            ov += wb * b2f(obuf[b * SD + (size_t)s * DM + c]);
        }
        t[(size_t)s * DM + c] = f2b(ov / wsum);
    }
}

// ---------------------------------------------------- final double-LN, row 0
__global__ __launch_bounds__(256) void final_ln_kernel(
    const float* __restrict__ h,
    const float* __restrict__ g1, const float* __restrict__ b1,
    const float* __restrict__ g2, const float* __restrict__ b2,
    float* __restrict__ out)
{
    __shared__ float sbuf[4];
    const int tid = threadIdx.x;
    float x0 = h[tid], x1 = h[tid + 256], x2 = h[tid + 512];
    float m = block_reduce_sum(x0 + x1 + x2, sbuf) * (1.f / DM);
    float d0 = x0 - m, d1 = x1 - m, d2 = x2 - m;
    float var = block_reduce_sum(d0 * d0 + d1 * d1 + d2 * d2, sbuf) * (1.f / DM);
    float rs = rsqrtf(var + EPS);
    float y0 = d0 * rs * g1[tid]       + b1[tid];
    float y1 = d1 * rs * g1[tid + 256] + b1[tid + 256];
    float y2 = d2 * rs * g1[tid + 512] + b1[tid + 512];
    m = block_reduce_sum(y0 + y1 + y2, sbuf) * (1.f / DM);
    d0 = y0 - m; d1 = y1 - m; d2 = y2 - m;
    var = block_reduce_sum(d0 * d0 + d1 * d1 + d2 * d2, sbuf) * (1.f / DM);
    rs = rsqrtf(var + EPS);
    out[tid]       = d0 * rs * g2[tid]       + b2[tid];
    out[tid + 256] = d1 * rs * g2[tid + 256] + b2[tid + 256];
    out[tid + 512] = d2 * rs * g2[tid + 512] + b2[tid + 512];
}

// ---------------------------------------------------------------- launcher
extern "C" void kernel_launch(void* const* d_in, const int* in_sizes, int n_in,
                              void* d_out, int out_size, void* d_ws, size_t ws_size,
                              hipStream_t stream)
{
    (void)in_sizes; (void)n_in; (void)out_size; (void)ws_size;
    const float* x        = (const float*)d_in[0];
    const float* coords   = (const float*)d_in[1];
    const float* pos_emb  = (const float*)d_in[2];
    const float* cls_tok  = (const float*)d_in[3];
    const float* patch_w  = (const float*)d_in[4];
    const float* patch_b  = (const float*)d_in[5];
    const float* ln1_g    = (const float*)d_in[6];
    const float* ln1_b    = (const float*)d_in[7];
    const float* wq       = (const float*)d_in[8];
    const float* bq       = (const float*)d_in[9];
    const float* wk       = (const float*)d_in[10];
    const float* bk       = (const float*)d_in[11];
    const float* wv       = (const float*)d_in[12];
    const float* bv       = (const float*)d_in[13];
    const float* wo       = (const float*)d_in[14];
    const float* bo       = (const float*)d_in[15];
    const float* ln2_g    = (const float*)d_in[16];
    const float* ln2_b    = (const float*)d_in[17];
    const float* w1       = (const float*)d_in[18];
    const float* b1       = (const float*)d_in[19];
    const float* w2       = (const float*)d_in[20];
    const float* b2       = (const float*)d_in[21];
    const float* enc_g    = (const float*)d_in[22];
    const float* enc_b    = (const float*)d_in[23];
    const float* norm_g   = (const float*)d_in[24];
    const float* norm_b   = (const float*)d_in[25];
    float* out = (float*)d_out;

    const size_t SD = (size_t)S_LEN * DM;        // 3,145,728
    const size_t DD = (size_t)DM * DM;           // 589,824
    const size_t DF = (size_t)DM * FFND;         // 2,359,296

    char* p = (char*)d_ws;
    float* h   = (float*)p;              p += SD * 4;
    u16* t     = (u16*)p;                p += SD * 2;
    u16* qb    = (u16*)p;                p += SD * 2;
    u16* kb    = (u16*)p;                p += SD * 2;
    u16* vb    = (u16*)p;                p += SD * 2;
    float* lse = (float*)p;              p += (size_t)5 * S_LEN * NHEAD * 4;
    u16* obuf  = (u16*)p;                p += 5 * SD * 2;
    u16* ffn   = obuf;                   // aliases obuf (dead during FFN)
    u16* xb    = obuf;                   // aliases obuf (used only pre-layer0)
    u16* pwT   = (u16*)p;                p += (size_t)DIN * DM * 2;
    u16* wTdd  = (u16*)p;                p += 4 * DD * 2;
    u16* w1T   = (u16*)p;                p += DF * 2;
    u16* w2T   = (u16*)p;                p += DF * 2;

    // ---- prologue: convert x, transpose patch_w, patch embed, pos add
    cvt_bf16_kernel<<<2048, 256, 0, stream>>>(x, xb, (L_LEN * DIN) / 4);
    transpose_cvt<<<dim3(DM / 64, DIN / 64, 1), 256, 0, stream>>>(
        patch_w, patch_w, patch_w, patch_w, pwT, DIN, DM);
    gemm64_kernel<<<dim3(DM / 64, 32), 256, 0, stream>>>(
        xb, pwT, patch_b, nullptr, h + DM, nullptr, L_LEN, DM, DIN, 1.f, 0);
    posadd_kernel<<<S_LEN, 256, 0, stream>>>(h, coords, pos_emb, cls_tok);

    for (int l = 0; l < 4; ++l) {
        const size_t lDD = (size_t)l * DD;
        const size_t lDF = (size_t)l * DF;
        // weight transposes for this layer
        transpose_cvt<<<dim3(12, 12, 4), 256, 0, stream>>>(
            wq + lDD, wk + lDD, wv + lDD, wo + lDD, wTdd, DM, DM);
        transpose_cvt<<<dim3(FFND / 64, DM / 64, 1), 256, 0, stream>>>(
            w1 + lDF, w1 + lDF, w1 + lDF, w1 + lDF, w1T, DM, FFND);
        transpose_cvt<<<dim3(DM / 64, FFND / 64, 1), 256, 0, stream>>>(
            w2 + lDF, w2 + lDF, w2 + lDF, w2 + lDF, w2T, FFND, DM);

        ln_kernel<<<S_LEN, 256, 0, stream>>>(h, t, ln1_g + l * DM, ln1_b + l * DM);
        qkv_kernel<<<dim3(6, 32, 3), 256, 0, stream>>>(
            t, wTdd, wTdd + DD, wTdd + 2 * DD,
            bq + l * DM, bk + l * DM, bv + l * DM, qb, kb, vb);
        lse_init_kernel<<<(5 * S_LEN * NHEAD) / 256, 256, 0, stream>>>(lse);
        attn_kernel<<<1488, 256, 0, stream>>>(qb, kb, vb, obuf, lse);
        combine_kernel<<<S_LEN, 256, 0, stream>>>(obuf, lse, t);
        gemm64_kernel<<<dim3(12, 32), 256, 0, stream>>>(
            t, wTdd + 3 * DD, bo + l * DM, h, h, nullptr, S_LEN, DM, DM, 1.f, 0);
        ln_kernel<<<S_LEN, 256, 0, stream>>>(h, t, ln2_g + l * DM, ln2_b + l * DM);
        gemm128_kernel<<<dim3(24, 32), 256, 0, stream>>>(
            t, w1T, b1 + (size_t)l * FFND, nullptr, nullptr, ffn,
            S_LEN, FFND, DM, 1.f, 1);
        gemm64_kernel<<<dim3(12, 32), 256, 0, stream>>>(
            ffn, w2T, b2 + l * DM, h, h, nullptr, S_LEN, DM, FFND, 1.f, 0);
    }
    final_ln_kernel<<<1, 256, 0, stream>>>(h, enc_g, enc_b, norm_g, norm_b, out);
}

// Round 3
// 1313.008 us; speedup vs baseline: 10.1383x; 1.0424x over previous
//
#include <hip/hip_runtime.h>
#include <hip/hip_bf16.h>
#include <math.h>
#include <stdint.h>

#define S_LEN 4096
#define L_LEN 4095
#define DIN   1536
#define DM    768
#define NHEAD 12
#define HDIM  64
#define FFND  3072
#define NEGV  (-1e9f)
#define EPS   1e-5f

typedef unsigned short u16;
typedef unsigned int   u32;
typedef short short8 __attribute__((ext_vector_type(8)));
typedef float f32x4 __attribute__((ext_vector_type(4)));
typedef float f32x16 __attribute__((ext_vector_type(16)));
typedef int i32x2 __attribute__((ext_vector_type(2)));

// ---------------------------------------------------------------- helpers
__device__ __forceinline__ u16 f2b(float f) {
    union { float f; u32 u; } x; x.f = f;
    u32 r = (x.u + 0x7FFF + ((x.u >> 16) & 1)) >> 16;
    return (u16)r;
}
__device__ __forceinline__ float b2f(u16 v) {
    union { u32 u; float f; } x; x.u = ((u32)v) << 16;
    return x.f;
}
__device__ __forceinline__ float gelu_tanh(float x) {
    float x3 = x * x * x;
    return 0.5f * x * (1.f + tanhf(0.7978845608f * (x + 0.044715f * x3)));
}
__device__ __forceinline__ float block_reduce_sum(float v, float* sbuf) {
#pragma unroll
    for (int o = 32; o > 0; o >>= 1) v += __shfl_down(v, o, 64);
    __syncthreads();
    if ((threadIdx.x & 63) == 0) sbuf[threadIdx.x >> 6] = v;
    __syncthreads();
    return sbuf[0] + sbuf[1] + sbuf[2] + sbuf[3];
}
__device__ __forceinline__ void gload16(const void* g, void* l) {
    __builtin_amdgcn_global_load_lds((const __attribute__((address_space(1))) void*)g,
                                     (__attribute__((address_space(3))) void*)l,
                                     16, 0, 0);
}

// ---------------------------------------------------------------- GEMM (bf16 MFMA, B^T layout)
template <int BN>
__device__ __forceinline__ void gemm_bt(
    const u16* __restrict__ A, const u16* __restrict__ Bt,
    const float* __restrict__ bias, const float* __restrict__ res,
    float* __restrict__ outf, u16* __restrict__ outb,
    int M, int N, int K, float scale, int dogelu, int bx, int by)
{
    constexpr int NI = BN / 32;
    constexpr int BI = BN / 32;
    __shared__ u16 As[128 * 64];
    __shared__ u16 Bs[BN * 64];
    const int tid = threadIdx.x, wv = tid >> 6, l = tid & 63;
    const int bm = by * 128, bn = bx * BN;
    const int wm = wv >> 1, wn = wv & 1;

    f32x4 acc[4][NI];
#pragma unroll
    for (int i = 0; i < 4; ++i)
#pragma unroll
        for (int j = 0; j < NI; ++j) acc[i][j] = (f32x4){0.f, 0.f, 0.f, 0.f};

    for (int k0 = 0; k0 < K; k0 += 64) {
#pragma unroll
        for (int i = 0; i < 4; ++i) {
            int row = (wv * 4 + i) * 8 + (l >> 3);
            int col = ((l & 7) ^ (row & 7)) * 8;
            int grow = bm + row; if (grow > M - 1) grow = M - 1;
            gload16(A + (size_t)grow * K + k0 + col, &As[(wv * 4 + i) * 512]);
        }
#pragma unroll
        for (int i = 0; i < BI; ++i) {
            int row = (wv * BI + i) * 8 + (l >> 3);
            int col = ((l & 7) ^ (row & 7)) * 8;
            gload16(Bt + (size_t)(bn + row) * K + k0 + col, &Bs[(wv * BI + i) * 512]);
        }
        __syncthreads();
#pragma unroll
        for (int kc = 0; kc < 2; ++kc) {
            short8 a[4], b[NI];
#pragma unroll
            for (int mi = 0; mi < 4; ++mi) {
                int row = wm * 64 + mi * 16 + (l & 15);
                int off = ((l >> 4) * 16 + kc * 64) ^ ((row & 7) << 4);
                a[mi] = *(const short8*)&As[(row * 128 + off) >> 1];
            }
#pragma unroll
            for (int ni = 0; ni < NI; ++ni) {
                int row = wn * (BN / 2) + ni * 16 + (l & 15);
                int off = ((l >> 4) * 16 + kc * 64) ^ ((row & 7) << 4);
                b[ni] = *(const short8*)&Bs[(row * 128 + off) >> 1];
            }
#pragma unroll
            for (int mi = 0; mi < 4; ++mi)
#pragma unroll
                for (int ni = 0; ni < NI; ++ni)
                    acc[mi][ni] = __builtin_amdgcn_mfma_f32_16x16x32_bf16(
                        a[mi], b[ni], acc[mi][ni], 0, 0, 0);
        }
        __syncthreads();
    }
#pragma unroll
    for (int mi = 0; mi < 4; ++mi) {
#pragma unroll
        for (int rg = 0; rg < 4; ++rg) {
            int row = bm + wm * 64 + mi * 16 + (l >> 4) * 4 + rg;
            if (row >= M) continue;
#pragma unroll
            for (int ni = 0; ni < NI; ++ni) {
                int col = bn + wn * (BN / 2) + ni * 16 + (l & 15);
                float v = (acc[mi][ni][rg] + bias[col]) * scale;
                if (dogelu) v = gelu_tanh(v);
                if (res) v += res[(size_t)row * N + col];
                if (outf) outf[(size_t)row * N + col] = v;
                if (outb) outb[(size_t)row * N + col] = f2b(v);
            }
        }
    }
}

__global__ __launch_bounds__(256) void gemm128_kernel(
    const u16* __restrict__ A, const u16* __restrict__ Bt,
    const float* __restrict__ bias, const float* __restrict__ res,
    float* __restrict__ outf, u16* __restrict__ outb,
    int M, int N, int K, float scale, int dogelu)
{
    gemm_bt<128>(A, Bt, bias, res, outf, outb, M, N, K, scale, dogelu,
                 blockIdx.x, blockIdx.y);
}
__global__ __launch_bounds__(256) void gemm64_kernel(
    const u16* __restrict__ A, const u16* __restrict__ Bt,
    const float* __restrict__ bias, const float* __restrict__ res,
    float* __restrict__ outf, u16* __restrict__ outb,
    int M, int N, int K, float scale, int dogelu)
{
    gemm_bt<64>(A, Bt, bias, res, outf, outb, M, N, K, scale, dogelu,
                blockIdx.x, blockIdx.y);
}
__global__ __launch_bounds__(256) void qkv_kernel(
    const u16* __restrict__ t,
    const u16* __restrict__ wqT, const u16* __restrict__ wkT, const u16* __restrict__ wvT,
    const float* __restrict__ bq, const float* __restrict__ bk, const float* __restrict__ bv,
    u16* __restrict__ q, u16* __restrict__ k, u16* __restrict__ v)
{
    int z = blockIdx.z;
    const u16* B = (z == 0) ? wqT : (z == 1) ? wkT : wvT;
    const float* bias = (z == 0) ? bq : (z == 1) ? bk : bv;
    u16* C = (z == 0) ? q : (z == 1) ? k : v;
    // Q additionally scaled by HD^-0.5 * log2(e) so softmax can use exp2
    float scale = (z == 0) ? 0.125f * 1.4426950408889634f : 1.0f;
    gemm_bt<128>(t, B, bias, nullptr, nullptr, C, S_LEN, DM, DM, scale, 0,
                 blockIdx.x, blockIdx.y);
}

// ---------------------------------------------------------- transpose+convert
__global__ __launch_bounds__(256) void transpose_cvt(
    const float* __restrict__ s0, const float* __restrict__ s1,
    const float* __restrict__ s2, const float* __restrict__ s3,
    u16* __restrict__ dst, int K, int N)
{
    int z = blockIdx.z;
    const float* src = (z == 0) ? s0 : (z == 1) ? s1 : (z == 2) ? s2 : s3;
    u16* d = dst + (size_t)z * K * N;
    __shared__ float tile[64][65];
    const int t = threadIdx.x;
    const int tk = blockIdx.y * 64, tn = blockIdx.x * 64;
    const int r0 = t >> 4, c0 = (t & 15) * 4;
#pragma unroll
    for (int i = 0; i < 4; ++i) {
        const float* sp = &src[(size_t)(tk + r0 + i * 16) * N + tn + c0];
        tile[r0 + i * 16][c0 + 0] = sp[0];
        tile[r0 + i * 16][c0 + 1] = sp[1];
        tile[r0 + i * 16][c0 + 2] = sp[2];
        tile[r0 + i * 16][c0 + 3] = sp[3];
    }
    __syncthreads();
#pragma unroll
    for (int i = 0; i < 4; ++i) {
        int nr = r0 + i * 16;
        u32 lo = (u32)f2b(tile[c0 + 0][nr]) | ((u32)f2b(tile[c0 + 1][nr]) << 16);
        u32 hi = (u32)f2b(tile[c0 + 2][nr]) | ((u32)f2b(tile[c0 + 3][nr]) << 16);
        *(uint2*)&d[(size_t)(tn + nr) * K + tk + c0] = make_uint2(lo, hi);
    }
}

__global__ __launch_bounds__(256) void cvt_bf16_kernel(
    const float* __restrict__ x, u16* __restrict__ xb, int n4)
{
    int stride = gridDim.x * 256;
    for (int i = blockIdx.x * 256 + threadIdx.x; i < n4; i += stride) {
        float4 v = ((const float4*)x)[i];
        u32 lo = (u32)f2b(v.x) | ((u32)f2b(v.y) << 16);
        u32 hi = (u32)f2b(v.z) | ((u32)f2b(v.w) << 16);
        ((uint2*)xb)[i] = make_uint2(lo, hi);
    }
}

// ---------------------------------------------------------------- LayerNorm
__global__ __launch_bounds__(256) void ln_kernel(
    const float* __restrict__ in, u16* __restrict__ out,
    const float* __restrict__ g, const float* __restrict__ b)
{
    __shared__ float sbuf[4];
    const int s = blockIdx.x;
    const int tid = threadIdx.x;
    const float* row = in + (size_t)s * DM;
    float x0 = row[tid], x1 = row[tid + 256], x2 = row[tid + 512];
    float m = block_reduce_sum(x0 + x1 + x2, sbuf) * (1.f / DM);
    float d0 = x0 - m, d1 = x1 - m, d2 = x2 - m;
    float var = block_reduce_sum(d0 * d0 + d1 * d1 + d2 * d2, sbuf) * (1.f / DM);
    float rs = rsqrtf(var + EPS);
    u16* orow = out + (size_t)s * DM;
    orow[tid]       = f2b(d0 * rs * g[tid]       + b[tid]);
    orow[tid + 256] = f2b(d1 * rs * g[tid + 256] + b[tid + 256]);
    orow[tid + 512] = f2b(d2 * rs * g[tid + 512] + b[tid + 512]);
}

// ------------------------------------------------- pos-embed add + cls row
__global__ __launch_bounds__(256) void posadd_kernel(
    float* __restrict__ h, const float* __restrict__ coords,
    const float* __restrict__ pe, const float* __restrict__ cls)
{
    const int s = blockIdx.x;
    const int tid = threadIdx.x;
    if (s == 0) {
        for (int c = tid; c < DM; c += 256) h[c] = cls[c] + pe[c];
    } else {
        float c0 = floorf(coords[(size_t)(s - 1) * 2 + 0] * (1.f / 256.f));
        float c1 = floorf(coords[(size_t)(s - 1) * 2 + 1] * (1.f / 256.f));
        int pos = (int)(c0 * 128.f + c1) + 1;
        float* hr = h + (size_t)s * DM;
        const float* pr = pe + (size_t)pos * DM;
        for (int c = tid; c < DM; c += 256) hr[c] += pr[c];
    }
}

// ---------------------------------------------------------------- attention
__global__ __launch_bounds__(256) void lse_init_kernel(float* __restrict__ lse)
{
    lse[(size_t)blockIdx.x * 256 + threadIdx.x] = NEGV;
}

// Swapped-QK flash attention: one block = (branch, seg, head, 128-q tile),
// 4 waves x 32 queries.  S^T = mfma(K, Q) -> lane holds 16 scores of ONE
// query (col = lane&31); wave-uniform max + defer-THR=8; P stays in
// registers via cvt_pk_bf16 + permlane32_swap; PV = mfma(P, V).
__global__ __launch_bounds__(256) void attn_kernel(
    const u16* __restrict__ qb, const u16* __restrict__ kbuf, const u16* __restrict__ vb,
    u16* __restrict__ obuf, float* __restrict__ lse)
{
    __shared__ u16 Vt[64 * 64];      // [hd][key], swizzled ^((hd&7)<<4)
    __shared__ float dbuf[4][32];

    const int tid = threadIdx.x, wv = tid >> 6, l = tid & 63;
    const int lq = l & 31, lh = l >> 5;
    const int bid = blockIdx.x;
    int b, rem;
    if (bid < 384)      { b = 0; rem = bid; }
    else if (bid < 576) { b = 1; rem = bid - 384; }
    else if (bid < 672) { b = 2; rem = bid - 576; }
    else if (bid < 720) { b = 3; rem = bid - 672; }
    else                { b = 4; rem = bid - 720; }
    const int r = 1 << b;
    const int w = 1024 << b;
    const int qt = (b < 3) ? 8 : (b == 3 ? 4 : 2);
    const int nv = (b < 3) ? 1024 : (b == 3 ? 512 : 256);
    const int qtile = rem % qt; rem /= qt;
    const int head = rem % NHEAD;
    const int seg = rem / NHEAD;
    const int off = head & (r - 1);
    const size_t base = (size_t)seg * w + off;
    const int q0 = qtile * 128 + wv * 32;
    const size_t kstep = (size_t)r * DM;

    // Q fragments: B-operand, lane needs Q[q=lq][hd = lh*8+j + 16s]
    const size_t sq_l = base + (size_t)r * (q0 + lq);
    const u16* qp = qb + sq_l * DM + head * 64 + lh * 8;
    short8 qf[4];
#pragma unroll
    for (int s = 0; s < 4; ++s) qf[s] = *(const short8*)(qp + s * 16);

    // K per-lane base: row = base + r*lq, same hd offset pattern
    const u16* kp = kbuf + (base + (size_t)r * lq) * DM + head * 64 + lh * 8;

    f32x16 oacc0 = {0.f,0.f,0.f,0.f,0.f,0.f,0.f,0.f,0.f,0.f,0.f,0.f,0.f,0.f,0.f,0.f};
    f32x16 oacc1 = oacc0;
    float mw = -INFINITY, dl = 0.f;

    for (int kt = 0; kt < nv; kt += 64) {
        if (kt) __syncthreads();
        // ---- stage V^T [64hd][64key] (cooperative, packed u32, rotated)
        {
            int c = tid & 7, pp = tid >> 3;
            size_t vr0 = base + (size_t)r * (kt + 2 * pp);
            const u16* v0p = vb + vr0 * DM + head * 64 + c * 8;
            const u16* v1p = v0p + kstep;
            short8 va = *(const short8*)v0p;
            short8 vbv = *(const short8*)v1p;
#pragma unroll
            for (int j = 0; j < 8; ++j) {
                int i = (j + c) & 7;
                int hd = c * 8 + i;
                u32 val = (u32)(u16)va[i] | ((u32)(u16)vbv[i] << 16);
                int byte = (hd * 128) + ((pp * 4) ^ (i << 4));
                *(u32*)&Vt[byte >> 1] = val;
            }
        }
        __syncthreads();

        // ---- QK^T: S^T[64key][32q] in two 32-key blocks
        const u16* kbase = kp + (size_t)kt * kstep;
        f32x16 s0 = {0.f,0.f,0.f,0.f,0.f,0.f,0.f,0.f,0.f,0.f,0.f,0.f,0.f,0.f,0.f,0.f};
        f32x16 s1 = s0;
#pragma unroll
        for (int s = 0; s < 4; ++s) {
            short8 kf = *(const short8*)(kbase + s * 16);
            s0 = __builtin_amdgcn_mfma_f32_32x32x16_bf16(kf, qf[s], s0, 0, 0, 0);
        }
#pragma unroll
        for (int s = 0; s < 4; ++s) {
            short8 kf = *(const short8*)(kbase + 32 * kstep + s * 16);
            s1 = __builtin_amdgcn_mfma_f32_32x32x16_bf16(kf, qf[s], s1, 0, 0, 0);
        }

        // ---- softmax (log2 domain; Q pre-scaled by log2e/8)
        float mloc = s0[0];
#pragma unroll
        for (int i = 1; i < 16; ++i) mloc = fmaxf(mloc, s0[i]);
#pragma unroll
        for (int i = 0; i < 16; ++i) mloc = fmaxf(mloc, s1[i]);
        if (__any(mloc > mw + 8.f)) {
            float mn = mloc;
#pragma unroll
            for (int o = 1; o < 64; o <<= 1) mn = fmaxf(mn, __shfl_xor(mn, o, 64));
            float al = exp2f(mw - mn);
            mw = mn;
            dl *= al;
#pragma unroll
            for (int i = 0; i < 16; ++i) { oacc0[i] *= al; oacc1[i] *= al; }
        }
        float ds = 0.f;
#pragma unroll
        for (int i = 0; i < 16; ++i) { s0[i] = exp2f(s0[i] - mw); ds += s0[i]; }
#pragma unroll
        for (int i = 0; i < 16; ++i) { s1[i] = exp2f(s1[i] - mw); ds += s1[i]; }
        ds += __shfl_xor(ds, 32, 64);
        dl += ds;

        // ---- P -> bf16 fragments in-register (cvt_pk + permlane32_swap), PV
#pragma unroll
        for (int kb2 = 0; kb2 < 2; ++kb2) {
            u32 wd[8];
#pragma unroll
            for (int j = 0; j < 8; ++j) {
                float lo = (kb2 == 0) ? s0[2 * j] : s1[2 * j];
                float hi = (kb2 == 0) ? s0[2 * j + 1] : s1[2 * j + 1];
                asm("v_cvt_pk_bf16_f32 %0, %1, %2" : "=v"(wd[j]) : "v"(lo), "v"(hi));
            }
#pragma unroll
            for (int ks2 = 0; ks2 < 2; ++ks2) {
                i32x2 X = __builtin_amdgcn_permlane32_swap(
                    (int)wd[ks2 * 4 + 0], (int)wd[ks2 * 4 + 2], false, false);
                i32x2 Y = __builtin_amdgcn_permlane32_swap(
                    (int)wd[ks2 * 4 + 1], (int)wd[ks2 * 4 + 3], false, false);
                union { u32 u[4]; short8 s; } pk;
                pk.u[0] = (u32)X[0]; pk.u[1] = (u32)Y[0];
                pk.u[2] = (u32)X[1]; pk.u[3] = (u32)Y[1];
                const int tt = kb2 * 2 + ks2;      // 16-key step
#pragma unroll
                for (int hg = 0; hg < 2; ++hg) {
                    int row = hg * 32 + lq;
                    int byteoff = row * 128 + ((lh * 16 + tt * 32) ^ ((row & 7) << 4));
                    short8 vf = *(const short8*)&Vt[byteoff >> 1];
                    if (hg == 0)
                        oacc0 = __builtin_amdgcn_mfma_f32_32x32x16_bf16(pk.s, vf, oacc0, 0, 0, 0);
                    else
                        oacc1 = __builtin_amdgcn_mfma_f32_32x32x16_bf16(pk.s, vf, oacc1, 0, 0, 0);
                }
            }
        }
    }

    // ---- epilogue
    if (l < 32) dbuf[wv][lq] = dl;
    __syncthreads();
    u16* ob = obuf + (size_t)b * S_LEN * DM;
    float* lse_b = lse + (size_t)b * S_LEN * NHEAD;
    if (l < 32) lse_b[sq_l * NHEAD + head] = mw + log2f(dl);
#pragma unroll
    for (int reg = 0; reg < 16; ++reg) {
        int qloc = (reg & 3) + 8 * (reg >> 2) + 4 * lh;
        float invd = 1.f / dbuf[wv][qloc];
        size_t sq = base + (size_t)r * (q0 + qloc);
        u16* orow = ob + sq * DM + head * 64;
        orow[lq]      = f2b(oacc0[reg] * invd);
        orow[32 + lq] = f2b(oacc1[reg] * invd);
    }
}

// ---- LongNet combine (lse in log2 units -> exp2 weights; identical ratios)
__global__ __launch_bounds__(256) void combine_kernel(
    const u16* __restrict__ obuf, const float* __restrict__ lse,
    u16* __restrict__ t)
{
    const int s = blockIdx.x;
    const int tid = threadIdx.x;
    const size_t SD = (size_t)S_LEN * DM;
#pragma unroll
    for (int j = 0; j < 3; ++j) {
        int c = tid + j * 256;
        int head = c >> 6;
        float lv[5];
#pragma unroll
        for (int b = 0; b < 5; ++b)
            lv[b] = lse[((size_t)b * S_LEN + s) * NHEAD + head];
        float mx = fmaxf(fmaxf(fmaxf(lv[0], lv[1]), fmaxf(lv[2], lv[3])), lv[4]);
        float wsum = 0.f, ov = 0.f;
#pragma unroll
        for (int b = 0; b < 5; ++b) {
            float wb = exp2f(lv[b] - mx);
            wsum += wb;
            ov += wb * b2f(obuf[b * SD + (size_t)s * DM + c]);
        }
        t[(size_t)s * DM + c] = f2b(ov / wsum);
    }
}

// ---------------------------------------------------- final double-LN, row 0
__global__ __launch_bounds__(256) void final_ln_kernel(
    const float* __restrict__ h,
    const float* __restrict__ g1, const float* __restrict__ b1,
    const float* __restrict__ g2, const float* __restrict__ b2,
    float* __restrict__ out)
{
    __shared__ float sbuf[4];
    const int tid = threadIdx.x;
    float x0 = h[tid], x1 = h[tid + 256], x2 = h[tid + 512];
    float m = block_reduce_sum(x0 + x1 + x2, sbuf) * (1.f / DM);
    float d0 = x0 - m, d1 = x1 - m, d2 = x2 - m;
    float var = block_reduce_sum(d0 * d0 + d1 * d1 + d2 * d2, sbuf) * (1.f / DM);
    float rs = rsqrtf(var + EPS);
    float y0 = d0 * rs * g1[tid]       + b1[tid];
    float y1 = d1 * rs * g1[tid + 256] + b1[tid + 256];
    float y2 = d2 * rs * g1[tid + 512] + b1[tid + 512];
    m = block_reduce_sum(y0 + y1 + y2, sbuf) * (1.f / DM);
    d0 = y0 - m; d1 = y1 - m; d2 = y2 - m;
    var = block_reduce_sum(d0 * d0 + d1 * d1 + d2 * d2, sbuf) * (1.f / DM);
    rs = rsqrtf(var + EPS);
    out[tid]       = d0 * rs * g2[tid]       + b2[tid];
    out[tid + 256] = d1 * rs * g2[tid + 256] + b2[tid + 256];
    out[tid + 512] = d2 * rs * g2[tid + 512] + b2[tid + 512];
}

// ---------------------------------------------------------------- launcher
extern "C" void kernel_launch(void* const* d_in, const int* in_sizes, int n_in,
                              void* d_out, int out_size, void* d_ws, size_t ws_size,
                              hipStream_t stream)
{
    (void)in_sizes; (void)n_in; (void)out_size; (void)ws_size;
    const float* x        = (const float*)d_in[0];
    const float* coords   = (const float*)d_in[1];
    const float* pos_emb  = (const float*)d_in[2];
    const float* cls_tok  = (const float*)d_in[3];
    const float* patch_w  = (const float*)d_in[4];
    const float* patch_b  = (const float*)d_in[5];
    const float* ln1_g    = (const float*)d_in[6];
    const float* ln1_b    = (const float*)d_in[7];
    const float* wq       = (const float*)d_in[8];
    const float* bq       = (const float*)d_in[9];
    const float* wk       = (const float*)d_in[10];
    const float* bk       = (const float*)d_in[11];
    const float* wv       = (const float*)d_in[12];
    const float* bv       = (const float*)d_in[13];
    const float* wo       = (const float*)d_in[14];
    const float* bo       = (const float*)d_in[15];
    const float* ln2_g    = (const float*)d_in[16];
    const float* ln2_b    = (const float*)d_in[17];
    const float* w1       = (const float*)d_in[18];
    const float* b1       = (const float*)d_in[19];
    const float* w2       = (const float*)d_in[20];
    const float* b2       = (const float*)d_in[21];
    const float* enc_g    = (const float*)d_in[22];
    const float* enc_b    = (const float*)d_in[23];
    const float* norm_g   = (const float*)d_in[24];
    const float* norm_b   = (const float*)d_in[25];
    float* out = (float*)d_out;

    const size_t SD = (size_t)S_LEN * DM;
    const size_t DD = (size_t)DM * DM;
    const size_t DF = (size_t)DM * FFND;

    char* p = (char*)d_ws;
    float* h   = (float*)p;              p += SD * 4;
    u16* t     = (u16*)p;                p += SD * 2;
    u16* qb    = (u16*)p;                p += SD * 2;
    u16* kb    = (u16*)p;                p += SD * 2;
    u16* vb    = (u16*)p;                p += SD * 2;
    float* lse = (float*)p;              p += (size_t)5 * S_LEN * NHEAD * 4;
    u16* obuf  = (u16*)p;                p += 5 * SD * 2;
    u16* ffn   = obuf;
    u16* xb    = obuf;
    u16* pwT   = (u16*)p;                p += (size_t)DIN * DM * 2;
    u16* wTdd  = (u16*)p;                p += 4 * DD * 2;
    u16* w1T   = (u16*)p;                p += DF * 2;
    u16* w2T   = (u16*)p;                p += DF * 2;

    cvt_bf16_kernel<<<2048, 256, 0, stream>>>(x, xb, (L_LEN * DIN) / 4);
    transpose_cvt<<<dim3(DM / 64, DIN / 64, 1), 256, 0, stream>>>(
        patch_w, patch_w, patch_w, patch_w, pwT, DIN, DM);
    gemm64_kernel<<<dim3(DM / 64, 32), 256, 0, stream>>>(
        xb, pwT, patch_b, nullptr, h + DM, nullptr, L_LEN, DM, DIN, 1.f, 0);
    posadd_kernel<<<S_LEN, 256, 0, stream>>>(h, coords, pos_emb, cls_tok);

    for (int l = 0; l < 4; ++l) {
        const size_t lDD = (size_t)l * DD;
        const size_t lDF = (size_t)l * DF;
        transpose_cvt<<<dim3(12, 12, 4), 256, 0, stream>>>(
            wq + lDD, wk + lDD, wv + lDD, wo + lDD, wTdd, DM, DM);
        transpose_cvt<<<dim3(FFND / 64, DM / 64, 1), 256, 0, stream>>>(
            w1 + lDF, w1 + lDF, w1 + lDF, w1 + lDF, w1T, DM, FFND);
        transpose_cvt<<<dim3(DM / 64, FFND / 64, 1), 256, 0, stream>>>(
            w2 + lDF, w2 + lDF, w2 + lDF, w2 + lDF, w2T, FFND, DM);

        ln_kernel<<<S_LEN, 256, 0, stream>>>(h, t, ln1_g + l * DM, ln1_b + l * DM);
        qkv_kernel<<<dim3(6, 32, 3), 256, 0, stream>>>(
            t, wTdd, wTdd + DD, wTdd + 2 * DD,
            bq + l * DM, bk + l * DM, bv + l * DM, qb, kb, vb);
        lse_init_kernel<<<(5 * S_LEN * NHEAD) / 256, 256, 0, stream>>>(lse);
        attn_kernel<<<744, 256, 0, stream>>>(qb, kb, vb, obuf, lse);
        combine_kernel<<<S_LEN, 256, 0, stream>>>(obuf, lse, t);
        gemm64_kernel<<<dim3(12, 32), 256, 0, stream>>>(
            t, wTdd + 3 * DD, bo + l * DM, h, h, nullptr, S_LEN, DM, DM, 1.f, 0);
        ln_kernel<<<S_LEN, 256, 0, stream>>>(h, t, ln2_g + l * DM, ln2_b + l * DM);
        gemm128_kernel<<<dim3(24, 32), 256, 0, stream>>>(
            t, w1T, b1 + (size_t)l * FFND, nullptr, nullptr, ffn,
            S_LEN, FFND, DM, 1.f, 1);
        gemm64_kernel<<<dim3(12, 32), 256, 0, stream>>>(
            ffn, w2T, b2 + l * DM, h, h, nullptr, S_LEN, DM, FFND, 1.f, 0);
    }
    final_ln_kernel<<<1, 256, 0, stream>>>(h, enc_g, enc_b, norm_g, norm_b, out);
}

// Round 4
// 1220.495 us; speedup vs baseline: 10.9067x; 1.0758x over previous
//
#include <hip/hip_runtime.h>
#include <hip/hip_bf16.h>
#include <math.h>
#include <stdint.h>

#define S_LEN 4096
#define L_LEN 4095
#define DIN   1536
#define DM    768
#define NHEAD 12
#define HDIM  64
#define FFND  3072
#define NEGV  (-1e9f)
#define EPS   1e-5f

typedef unsigned short u16;
typedef unsigned int   u32;
typedef short short8 __attribute__((ext_vector_type(8)));
typedef float f32x4 __attribute__((ext_vector_type(4)));
typedef float f32x16 __attribute__((ext_vector_type(16)));
typedef int i32x2 __attribute__((ext_vector_type(2)));

// ---------------------------------------------------------------- helpers
__device__ __forceinline__ u16 f2b(float f) {
    union { float f; u32 u; } x; x.f = f;
    u32 r = (x.u + 0x7FFF + ((x.u >> 16) & 1)) >> 16;
    return (u16)r;
}
__device__ __forceinline__ float b2f(u16 v) {
    union { u32 u; float f; } x; x.u = ((u32)v) << 16;
    return x.f;
}
__device__ __forceinline__ float gelu_tanh(float x) {
    float x3 = x * x * x;
    return 0.5f * x * (1.f + tanhf(0.7978845608f * (x + 0.044715f * x3)));
}
__device__ __forceinline__ float block_reduce_sum(float v, float* sbuf) {
#pragma unroll
    for (int o = 32; o > 0; o >>= 1) v += __shfl_down(v, o, 64);
    __syncthreads();
    if ((threadIdx.x & 63) == 0) sbuf[threadIdx.x >> 6] = v;
    __syncthreads();
    return sbuf[0] + sbuf[1] + sbuf[2] + sbuf[3];
}
__device__ __forceinline__ void gload16(const void* g, void* l) {
    __builtin_amdgcn_global_load_lds((const __attribute__((address_space(1))) void*)g,
                                     (__attribute__((address_space(3))) void*)l,
                                     16, 0, 0);
}

// ---------------------------------------------------------------- GEMM (bf16 MFMA, B^T layout)
template <int BN>
__device__ __forceinline__ void gemm_bt(
    const u16* __restrict__ A, const u16* __restrict__ Bt,
    const float* __restrict__ bias, const float* __restrict__ res,
    float* __restrict__ outf, u16* __restrict__ outb,
    int M, int N, int K, float scale, int dogelu, int bx, int by)
{
    constexpr int NI = BN / 32;
    constexpr int BI = BN / 32;
    __shared__ u16 As[128 * 64];
    __shared__ u16 Bs[BN * 64];
    const int tid = threadIdx.x, wv = tid >> 6, l = tid & 63;
    const int bm = by * 128, bn = bx * BN;
    const int wm = wv >> 1, wn = wv & 1;

    f32x4 acc[4][NI];
#pragma unroll
    for (int i = 0; i < 4; ++i)
#pragma unroll
        for (int j = 0; j < NI; ++j) acc[i][j] = (f32x4){0.f, 0.f, 0.f, 0.f};

    for (int k0 = 0; k0 < K; k0 += 64) {
#pragma unroll
        for (int i = 0; i < 4; ++i) {
            int row = (wv * 4 + i) * 8 + (l >> 3);
            int col = ((l & 7) ^ (row & 7)) * 8;
            int grow = bm + row; if (grow > M - 1) grow = M - 1;
            gload16(A + (size_t)grow * K + k0 + col, &As[(wv * 4 + i) * 512]);
        }
#pragma unroll
        for (int i = 0; i < BI; ++i) {
            int row = (wv * BI + i) * 8 + (l >> 3);
            int col = ((l & 7) ^ (row & 7)) * 8;
            gload16(Bt + (size_t)(bn + row) * K + k0 + col, &Bs[(wv * BI + i) * 512]);
        }
        __syncthreads();
#pragma unroll
        for (int kc = 0; kc < 2; ++kc) {
            short8 a[4], b[NI];
#pragma unroll
            for (int mi = 0; mi < 4; ++mi) {
                int row = wm * 64 + mi * 16 + (l & 15);
                int off = ((l >> 4) * 16 + kc * 64) ^ ((row & 7) << 4);
                a[mi] = *(const short8*)&As[(row * 128 + off) >> 1];
            }
#pragma unroll
            for (int ni = 0; ni < NI; ++ni) {
                int row = wn * (BN / 2) + ni * 16 + (l & 15);
                int off = ((l >> 4) * 16 + kc * 64) ^ ((row & 7) << 4);
                b[ni] = *(const short8*)&Bs[(row * 128 + off) >> 1];
            }
#pragma unroll
            for (int mi = 0; mi < 4; ++mi)
#pragma unroll
                for (int ni = 0; ni < NI; ++ni)
                    acc[mi][ni] = __builtin_amdgcn_mfma_f32_16x16x32_bf16(
                        a[mi], b[ni], acc[mi][ni], 0, 0, 0);
        }
        __syncthreads();
    }
#pragma unroll
    for (int mi = 0; mi < 4; ++mi) {
#pragma unroll
        for (int rg = 0; rg < 4; ++rg) {
            int row = bm + wm * 64 + mi * 16 + (l >> 4) * 4 + rg;
            if (row >= M) continue;
#pragma unroll
            for (int ni = 0; ni < NI; ++ni) {
                int col = bn + wn * (BN / 2) + ni * 16 + (l & 15);
                float v = (acc[mi][ni][rg] + bias[col]) * scale;
                if (dogelu) v = gelu_tanh(v);
                if (res) v += res[(size_t)row * N + col];
                if (outf) outf[(size_t)row * N + col] = v;
                if (outb) outb[(size_t)row * N + col] = f2b(v);
            }
        }
    }
}

__global__ __launch_bounds__(256) void gemm128_kernel(
    const u16* __restrict__ A, const u16* __restrict__ Bt,
    const float* __restrict__ bias, const float* __restrict__ res,
    float* __restrict__ outf, u16* __restrict__ outb,
    int M, int N, int K, float scale, int dogelu)
{
    gemm_bt<128>(A, Bt, bias, res, outf, outb, M, N, K, scale, dogelu,
                 blockIdx.x, blockIdx.y);
}
__global__ __launch_bounds__(256) void gemm64_kernel(
    const u16* __restrict__ A, const u16* __restrict__ Bt,
    const float* __restrict__ bias, const float* __restrict__ res,
    float* __restrict__ outf, u16* __restrict__ outb,
    int M, int N, int K, float scale, int dogelu)
{
    gemm_bt<64>(A, Bt, bias, res, outf, outb, M, N, K, scale, dogelu,
                blockIdx.x, blockIdx.y);
}
__global__ __launch_bounds__(256) void qkv_kernel(
    const u16* __restrict__ t,
    const u16* __restrict__ wqT, const u16* __restrict__ wkT, const u16* __restrict__ wvT,
    const float* __restrict__ bq, const float* __restrict__ bk, const float* __restrict__ bv,
    u16* __restrict__ q, u16* __restrict__ k, u16* __restrict__ v)
{
    int z = blockIdx.z;
    const u16* B = (z == 0) ? wqT : (z == 1) ? wkT : wvT;
    const float* bias = (z == 0) ? bq : (z == 1) ? bk : bv;
    u16* C = (z == 0) ? q : (z == 1) ? k : v;
    // Q additionally scaled by HD^-0.5 * log2(e) so softmax can use exp2
    float scale = (z == 0) ? 0.125f * 1.4426950408889634f : 1.0f;
    gemm_bt<128>(t, B, bias, nullptr, nullptr, C, S_LEN, DM, DM, scale, 0,
                 blockIdx.x, blockIdx.y);
}

// ---------------------------------------------------------- transpose+convert
__global__ __launch_bounds__(256) void transpose_cvt(
    const float* __restrict__ s0, const float* __restrict__ s1,
    const float* __restrict__ s2, const float* __restrict__ s3,
    u16* __restrict__ dst, int K, int N)
{
    int z = blockIdx.z;
    const float* src = (z == 0) ? s0 : (z == 1) ? s1 : (z == 2) ? s2 : s3;
    u16* d = dst + (size_t)z * K * N;
    __shared__ float tile[64][65];
    const int t = threadIdx.x;
    const int tk = blockIdx.y * 64, tn = blockIdx.x * 64;
    const int r0 = t >> 4, c0 = (t & 15) * 4;
#pragma unroll
    for (int i = 0; i < 4; ++i) {
        const float* sp = &src[(size_t)(tk + r0 + i * 16) * N + tn + c0];
        tile[r0 + i * 16][c0 + 0] = sp[0];
        tile[r0 + i * 16][c0 + 1] = sp[1];
        tile[r0 + i * 16][c0 + 2] = sp[2];
        tile[r0 + i * 16][c0 + 3] = sp[3];
    }
    __syncthreads();
#pragma unroll
    for (int i = 0; i < 4; ++i) {
        int nr = r0 + i * 16;
        u32 lo = (u32)f2b(tile[c0 + 0][nr]) | ((u32)f2b(tile[c0 + 1][nr]) << 16);
        u32 hi = (u32)f2b(tile[c0 + 2][nr]) | ((u32)f2b(tile[c0 + 3][nr]) << 16);
        *(uint2*)&d[(size_t)(tn + nr) * K + tk + c0] = make_uint2(lo, hi);
    }
}

// merged per-layer weight transpose: wq/wk/wv/wo (768x768) + w1 (768x3072) + w2 (3072x768)
__global__ __launch_bounds__(256) void prep_weights(
    const float* __restrict__ wq, const float* __restrict__ wk,
    const float* __restrict__ wv, const float* __restrict__ wo,
    const float* __restrict__ w1, const float* __restrict__ w2,
    u16* __restrict__ wTdd, u16* __restrict__ w1T, u16* __restrict__ w2T)
{
    __shared__ float tile[64][65];
    const int id = blockIdx.x;
    const float* src; u16* dst; int K, N, tk64, tn64;
    if (id < 576) {
        int z = id / 144, rm = id % 144;
        src = (z == 0) ? wq : (z == 1) ? wk : (z == 2) ? wv : wo;
        dst = wTdd + (size_t)z * DM * DM;
        K = DM; N = DM; tk64 = rm / 12; tn64 = rm % 12;
    } else if (id < 1152) {
        int rm = id - 576;
        src = w1; dst = w1T; K = DM; N = FFND; tk64 = rm / 48; tn64 = rm % 48;
    } else {
        int rm = id - 1152;
        src = w2; dst = w2T; K = FFND; N = DM; tk64 = rm / 12; tn64 = rm % 12;
    }
    const int t = threadIdx.x;
    const int tk = tk64 * 64, tn = tn64 * 64;
    const int r0 = t >> 4, c0 = (t & 15) * 4;
#pragma unroll
    for (int i = 0; i < 4; ++i) {
        const float* sp = &src[(size_t)(tk + r0 + i * 16) * N + tn + c0];
        tile[r0 + i * 16][c0 + 0] = sp[0];
        tile[r0 + i * 16][c0 + 1] = sp[1];
        tile[r0 + i * 16][c0 + 2] = sp[2];
        tile[r0 + i * 16][c0 + 3] = sp[3];
    }
    __syncthreads();
#pragma unroll
    for (int i = 0; i < 4; ++i) {
        int nr = r0 + i * 16;
        u32 lo = (u32)f2b(tile[c0 + 0][nr]) | ((u32)f2b(tile[c0 + 1][nr]) << 16);
        u32 hi = (u32)f2b(tile[c0 + 2][nr]) | ((u32)f2b(tile[c0 + 3][nr]) << 16);
        *(uint2*)&dst[(size_t)(tn + nr) * K + tk + c0] = make_uint2(lo, hi);
    }
}

__global__ __launch_bounds__(256) void cvt_bf16_kernel(
    const float* __restrict__ x, u16* __restrict__ xb, int n4)
{
    int stride = gridDim.x * 256;
    for (int i = blockIdx.x * 256 + threadIdx.x; i < n4; i += stride) {
        float4 v = ((const float4*)x)[i];
        u32 lo = (u32)f2b(v.x) | ((u32)f2b(v.y) << 16);
        u32 hi = (u32)f2b(v.z) | ((u32)f2b(v.w) << 16);
        ((uint2*)xb)[i] = make_uint2(lo, hi);
    }
}

// ---------------------------------------------------------------- LayerNorm (f32 in -> bf16 out)
__global__ __launch_bounds__(192) void ln_kernel(
    const float* __restrict__ in, u16* __restrict__ out,
    const float* __restrict__ g, const float* __restrict__ b)
{
    __shared__ float sA[3], sB[3];
    const int s = blockIdx.x, tid = threadIdx.x;
    float4 x = ((const float4*)(in + (size_t)s * DM))[tid];
    float sum = x.x + x.y + x.z + x.w;
#pragma unroll
    for (int o = 32; o > 0; o >>= 1) sum += __shfl_down(sum, o, 64);
    if ((tid & 63) == 0) sA[tid >> 6] = sum;
    __syncthreads();
    float m = (sA[0] + sA[1] + sA[2]) * (1.f / DM);
    float dx = x.x - m, dy = x.y - m, dz = x.z - m, dw = x.w - m;
    float vs = dx * dx + dy * dy + dz * dz + dw * dw;
#pragma unroll
    for (int o = 32; o > 0; o >>= 1) vs += __shfl_down(vs, o, 64);
    if ((tid & 63) == 0) sB[tid >> 6] = vs;
    __syncthreads();
    float rs = rsqrtf((sB[0] + sB[1] + sB[2]) * (1.f / DM) + EPS);
    float4 gv = ((const float4*)g)[tid];
    float4 bv = ((const float4*)b)[tid];
    u32 lo = (u32)f2b(dx * rs * gv.x + bv.x) | ((u32)f2b(dy * rs * gv.y + bv.y) << 16);
    u32 hi = (u32)f2b(dz * rs * gv.z + bv.z) | ((u32)f2b(dw * rs * gv.w + bv.w) << 16);
    ((uint2*)(out + (size_t)s * DM))[tid] = make_uint2(lo, hi);
}

// ------------------------------------------------- pos-embed add + cls row
__global__ __launch_bounds__(256) void posadd_kernel(
    float* __restrict__ h, const float* __restrict__ coords,
    const float* __restrict__ pe, const float* __restrict__ cls)
{
    const int s = blockIdx.x;
    const int tid = threadIdx.x;
    if (s == 0) {
        for (int c = tid; c < DM; c += 256) h[c] = cls[c] + pe[c];
    } else {
        float c0 = floorf(coords[(size_t)(s - 1) * 2 + 0] * (1.f / 256.f));
        float c1 = floorf(coords[(size_t)(s - 1) * 2 + 1] * (1.f / 256.f));
        int pos = (int)(c0 * 128.f + c1) + 1;
        float* hr = h + (size_t)s * DM;
        const float* pr = pe + (size_t)pos * DM;
        for (int c = tid; c < DM; c += 256) hr[c] += pr[c];
    }
}

// ---------------------------------------------------------------- attention
__global__ __launch_bounds__(256) void lse_init_kernel(float* __restrict__ lse)
{
    lse[(size_t)blockIdx.x * 256 + threadIdx.x] = NEGV;
}

// Swapped-QK flash attention, pipelined:
//   V^T double-buffered in LDS (loaded global->reg two tiles ahead),
//   K fragments reloaded right after QK^T consumes them (hidden under
//   softmax+PV+barrier), ONE barrier per key tile.
__global__ __launch_bounds__(256, 3) void attn_kernel(
    const u16* __restrict__ qb, const u16* __restrict__ kbuf, const u16* __restrict__ vb,
    u16* __restrict__ obuf, float* __restrict__ lse)
{
    __shared__ u16 Vt[2][64 * 64];   // [buf][hd][key] swizzled
    __shared__ float dbuf[4][32];

    const int tid = threadIdx.x, wv = tid >> 6, l = tid & 63;
    const int lq = l & 31, lh = l >> 5;
    const int bid = blockIdx.x;
    int b, rem;
    if (bid < 384)      { b = 0; rem = bid; }
    else if (bid < 576) { b = 1; rem = bid - 384; }
    else if (bid < 672) { b = 2; rem = bid - 576; }
    else if (bid < 720) { b = 3; rem = bid - 672; }
    else                { b = 4; rem = bid - 720; }
    const int r = 1 << b;
    const int w = 1024 << b;
    const int qt = (b < 3) ? 8 : (b == 3 ? 4 : 2);
    const int nv = (b < 3) ? 1024 : (b == 3 ? 512 : 256);
    const int qtile = rem % qt; rem /= qt;
    const int head = rem % NHEAD;
    const int seg = rem / NHEAD;
    const int off = head & (r - 1);
    const size_t base = (size_t)seg * w + off;
    const int q0 = qtile * 128 + wv * 32;
    const size_t kstep = (size_t)r * DM;
    const int ntiles = nv >> 6;

    // Q fragments: B-operand, lane needs Q[q=lq][hd = lh*8+j + 16s]
    const size_t sq_l = base + (size_t)r * (q0 + lq);
    const u16* qp = qb + sq_l * DM + head * 64 + lh * 8;
    short8 qf[4];
#pragma unroll
    for (int s = 0; s < 4; ++s) qf[s] = *(const short8*)(qp + s * 16);

    // K per-lane base
    const u16* kp = kbuf + (base + (size_t)r * lq) * DM + head * 64 + lh * 8;
    // V staging role: c = hd chunk (8), pp = key pair (32)
    const int c = tid & 7, pp = tid >> 3;
    const u16* vsrc = vb + (base + (size_t)r * (2 * pp)) * DM + head * 64 + c * 8;

#define VPACK(dstbuf, A8, B8) do {                                          \
    _Pragma("unroll") for (int j = 0; j < 8; ++j) {                         \
        int i_ = (j + c) & 7; int hd_ = c * 8 + i_;                         \
        u32 val_ = (u32)(u16)(A8)[i_] | ((u32)(u16)(B8)[i_] << 16);         \
        int byte_ = hd_ * 128 + ((pp * 4) ^ (i_ << 4));                     \
        *(u32*)&Vt[dstbuf][byte_ >> 1] = val_; } } while (0)

    f32x16 oacc0 = {0.f,0.f,0.f,0.f,0.f,0.f,0.f,0.f,0.f,0.f,0.f,0.f,0.f,0.f,0.f,0.f};
    f32x16 oacc1 = oacc0;
    float mw = -INFINITY, dl = 0.f;

    // ---- prologue: V(0) -> B0, V(1) -> regs, K(0) -> regs
    short8 van = *(const short8*)vsrc;
    short8 vbn = *(const short8*)(vsrc + kstep);
    VPACK(0, van, vbn);
    van = *(const short8*)(vsrc + 64 * kstep);
    vbn = *(const short8*)(vsrc + 65 * kstep);
    short8 kf[8];
#pragma unroll
    for (int s = 0; s < 4; ++s) {
        kf[s]     = *(const short8*)(kp + s * 16);
        kf[4 + s] = *(const short8*)(kp + 32 * kstep + s * 16);
    }
    __syncthreads();

    for (int t = 0; t < ntiles; ++t) {
        const int curb = t & 1;
        // ---- QK^T with current K fragments
        f32x16 s0 = {0.f,0.f,0.f,0.f,0.f,0.f,0.f,0.f,0.f,0.f,0.f,0.f,0.f,0.f,0.f,0.f};
        f32x16 s1 = s0;
#pragma unroll
        for (int s = 0; s < 4; ++s)
            s0 = __builtin_amdgcn_mfma_f32_32x32x16_bf16(kf[s], qf[s], s0, 0, 0, 0);
#pragma unroll
        for (int s = 0; s < 4; ++s)
            s1 = __builtin_amdgcn_mfma_f32_32x32x16_bf16(kf[4 + s], qf[s], s1, 0, 0, 0);

        // ---- prefetch K(t+1): latency hidden under softmax+PV+barrier
        if (t + 1 < ntiles) {
            const u16* kn = kp + (size_t)(t + 1) * 64 * kstep;
#pragma unroll
            for (int s = 0; s < 4; ++s) {
                kf[s]     = *(const short8*)(kn + s * 16);
                kf[4 + s] = *(const short8*)(kn + 32 * kstep + s * 16);
            }
        }

        // ---- softmax (log2 domain)
        float mloc = s0[0];
#pragma unroll
        for (int i = 1; i < 16; ++i) mloc = fmaxf(mloc, s0[i]);
#pragma unroll
        for (int i = 0; i < 16; ++i) mloc = fmaxf(mloc, s1[i]);
        if (__any(mloc > mw + 8.f)) {
            float mn = mloc;
#pragma unroll
            for (int o = 1; o < 64; o <<= 1) mn = fmaxf(mn, __shfl_xor(mn, o, 64));
            float al = exp2f(mw - mn);
            mw = mn;
            dl *= al;
#pragma unroll
            for (int i = 0; i < 16; ++i) { oacc0[i] *= al; oacc1[i] *= al; }
        }
        float ds = 0.f;
#pragma unroll
        for (int i = 0; i < 16; ++i) { s0[i] = exp2f(s0[i] - mw); ds += s0[i]; }
#pragma unroll
        for (int i = 0; i < 16; ++i) { s1[i] = exp2f(s1[i] - mw); ds += s1[i]; }
        ds += __shfl_xor(ds, 32, 64);
        dl += ds;

        // ---- write V^T(t+1) into spare buffer, then load V(t+2) to regs
        if (t + 1 < ntiles) VPACK(curb ^ 1, van, vbn);
        if (t + 2 < ntiles) {
            van = *(const short8*)(vsrc + (size_t)(t + 2) * 64 * kstep);
            vbn = *(const short8*)(vsrc + ((size_t)(t + 2) * 64 + 1) * kstep);
        }

        // ---- P -> bf16 fragments in-register, PV from Vt[curb]
#pragma unroll
        for (int kb2 = 0; kb2 < 2; ++kb2) {
            u32 wd[8];
#pragma unroll
            for (int j = 0; j < 8; ++j) {
                float lo = (kb2 == 0) ? s0[2 * j] : s1[2 * j];
                float hi = (kb2 == 0) ? s0[2 * j + 1] : s1[2 * j + 1];
                asm("v_cvt_pk_bf16_f32 %0, %1, %2" : "=v"(wd[j]) : "v"(lo), "v"(hi));
            }
#pragma unroll
            for (int ks2 = 0; ks2 < 2; ++ks2) {
                i32x2 X = __builtin_amdgcn_permlane32_swap(
                    (int)wd[ks2 * 4 + 0], (int)wd[ks2 * 4 + 2], false, false);
                i32x2 Y = __builtin_amdgcn_permlane32_swap(
                    (int)wd[ks2 * 4 + 1], (int)wd[ks2 * 4 + 3], false, false);
                union { u32 u[4]; short8 s; } pk;
                pk.u[0] = (u32)X[0]; pk.u[1] = (u32)Y[0];
                pk.u[2] = (u32)X[1]; pk.u[3] = (u32)Y[1];
                const int tt = kb2 * 2 + ks2;
#pragma unroll
                for (int hg = 0; hg < 2; ++hg) {
                    int row = hg * 32 + lq;
                    int byteoff = row * 128 + ((lh * 16 + tt * 32) ^ ((row & 7) << 4));
                    short8 vf = *(const short8*)&Vt[curb][byteoff >> 1];
                    if (hg == 0)
                        oacc0 = __builtin_amdgcn_mfma_f32_32x32x16_bf16(pk.s, vf, oacc0, 0, 0, 0);
                    else
                        oacc1 = __builtin_amdgcn_mfma_f32_32x32x16_bf16(pk.s, vf, oacc1, 0, 0, 0);
                }
            }
        }
        __syncthreads();
    }

    // ---- epilogue (dbuf is same-wave only: no barrier needed)
    if (l < 32) dbuf[wv][lq] = dl;
    u16* ob = obuf + (size_t)b * S_LEN * DM;
    float* lse_b = lse + (size_t)b * S_LEN * NHEAD;
    if (l < 32) lse_b[sq_l * NHEAD + head] = mw + log2f(dl);
#pragma unroll
    for (int reg = 0; reg < 16; ++reg) {
        int qloc = (reg & 3) + 8 * (reg >> 2) + 4 * lh;
        float invd = 1.f / dbuf[wv][qloc];
        size_t sq = base + (size_t)r * (q0 + qloc);
        u16* orow = ob + sq * DM + head * 64;
        orow[lq]      = f2b(oacc0[reg] * invd);
        orow[32 + lq] = f2b(oacc1[reg] * invd);
    }
#undef VPACK
}

// ---- LongNet combine (lse in log2 units; skip branches never written)
__global__ __launch_bounds__(192) void combine_kernel(
    const u16* __restrict__ obuf, const float* __restrict__ lse,
    u16* __restrict__ t)
{
    const int s = blockIdx.x;
    const int tid = threadIdx.x;
    const int c0 = tid * 4, head = c0 >> 6;
    const size_t SD = (size_t)S_LEN * DM;
    float lv[5];
#pragma unroll
    for (int b = 0; b < 5; ++b)
        lv[b] = lse[((size_t)b * S_LEN + s) * NHEAD + head];
    float mx = fmaxf(fmaxf(fmaxf(lv[0], lv[1]), fmaxf(lv[2], lv[3])), lv[4]);
    float wsum = 0.f, o0 = 0.f, o1 = 0.f, o2 = 0.f, o3 = 0.f;
#pragma unroll
    for (int b = 0; b < 5; ++b) {
        if (lv[b] > -1e8f) {
            float wb = exp2f(lv[b] - mx);
            wsum += wb;
            uint2 u = *(const uint2*)(obuf + b * SD + (size_t)s * DM + c0);
            o0 += wb * b2f((u16)(u.x & 0xffff));
            o1 += wb * b2f((u16)(u.x >> 16));
            o2 += wb * b2f((u16)(u.y & 0xffff));
            o3 += wb * b2f((u16)(u.y >> 16));
        }
    }
    float inv = 1.f / wsum;
    u32 lo = (u32)f2b(o0 * inv) | ((u32)f2b(o1 * inv) << 16);
    u32 hi = (u32)f2b(o2 * inv) | ((u32)f2b(o3 * inv) << 16);
    ((uint2*)(t + (size_t)s * DM))[tid] = make_uint2(lo, hi);
}

// ---------------------------------------------------- final double-LN, row 0
__global__ __launch_bounds__(256) void final_ln_kernel(
    const float* __restrict__ h,
    const float* __restrict__ g1, const float* __restrict__ b1,
    const float* __restrict__ g2, const float* __restrict__ b2,
    float* __restrict__ out)
{
    __shared__ float sbuf[4];
    const int tid = threadIdx.x;
    float x0 = h[tid], x1 = h[tid + 256], x2 = h[tid + 512];
    float m = block_reduce_sum(x0 + x1 + x2, sbuf) * (1.f / DM);
    float d0 = x0 - m, d1 = x1 - m, d2 = x2 - m;
    float var = block_reduce_sum(d0 * d0 + d1 * d1 + d2 * d2, sbuf) * (1.f / DM);
    float rs = rsqrtf(var + EPS);
    float y0 = d0 * rs * g1[tid]       + b1[tid];
    float y1 = d1 * rs * g1[tid + 256] + b1[tid + 256];
    float y2 = d2 * rs * g1[tid + 512] + b1[tid + 512];
    m = block_reduce_sum(y0 + y1 + y2, sbuf) * (1.f / DM);
    d0 = y0 - m; d1 = y1 - m; d2 = y2 - m;
    var = block_reduce_sum(d0 * d0 + d1 * d1 + d2 * d2, sbuf) * (1.f / DM);
    rs = rsqrtf(var + EPS);
    out[tid]       = d0 * rs * g2[tid]       + b2[tid];
    out[tid + 256] = d1 * rs * g2[tid + 256] + b2[tid + 256];
    out[tid + 512] = d2 * rs * g2[tid + 512] + b2[tid + 512];
}

// ---------------------------------------------------------------- launcher
extern "C" void kernel_launch(void* const* d_in, const int* in_sizes, int n_in,
                              void* d_out, int out_size, void* d_ws, size_t ws_size,
                              hipStream_t stream)
{
    (void)in_sizes; (void)n_in; (void)out_size; (void)ws_size;
    const float* x        = (const float*)d_in[0];
    const float* coords   = (const float*)d_in[1];
    const float* pos_emb  = (const float*)d_in[2];
    const float* cls_tok  = (const float*)d_in[3];
    const float* patch_w  = (const float*)d_in[4];
    const float* patch_b  = (const float*)d_in[5];
    const float* ln1_g    = (const float*)d_in[6];
    const float* ln1_b    = (const float*)d_in[7];
    const float* wq       = (const float*)d_in[8];
    const float* bq       = (const float*)d_in[9];
    const float* wk       = (const float*)d_in[10];
    const float* bk       = (const float*)d_in[11];
    const float* wv       = (const float*)d_in[12];
    const float* bv       = (const float*)d_in[13];
    const float* wo       = (const float*)d_in[14];
    const float* bo       = (const float*)d_in[15];
    const float* ln2_g    = (const float*)d_in[16];
    const float* ln2_b    = (const float*)d_in[17];
    const float* w1       = (const float*)d_in[18];
    const float* b1       = (const float*)d_in[19];
    const float* w2       = (const float*)d_in[20];
    const float* b2       = (const float*)d_in[21];
    const float* enc_g    = (const float*)d_in[22];
    const float* enc_b    = (const float*)d_in[23];
    const float* norm_g   = (const float*)d_in[24];
    const float* norm_b   = (const float*)d_in[25];
    float* out = (float*)d_out;

    const size_t SD = (size_t)S_LEN * DM;
    const size_t DD = (size_t)DM * DM;
    const size_t DF = (size_t)DM * FFND;

    char* p = (char*)d_ws;
    float* h   = (float*)p;              p += SD * 4;
    u16* t     = (u16*)p;                p += SD * 2;
    u16* qb    = (u16*)p;                p += SD * 2;
    u16* kb    = (u16*)p;                p += SD * 2;
    u16* vb    = (u16*)p;                p += SD * 2;
    float* lse = (float*)p;              p += (size_t)5 * S_LEN * NHEAD * 4;
    u16* obuf  = (u16*)p;                p += 5 * SD * 2;
    u16* ffn   = obuf;
    u16* xb    = obuf;
    u16* pwT   = (u16*)p;                p += (size_t)DIN * DM * 2;
    u16* wTdd  = (u16*)p;                p += 4 * DD * 2;
    u16* w1T   = (u16*)p;                p += DF * 2;
    u16* w2T   = (u16*)p;                p += DF * 2;

    cvt_bf16_kernel<<<2048, 256, 0, stream>>>(x, xb, (L_LEN * DIN) / 4);
    transpose_cvt<<<dim3(DM / 64, DIN / 64, 1), 256, 0, stream>>>(
        patch_w, patch_w, patch_w, patch_w, pwT, DIN, DM);
    gemm64_kernel<<<dim3(DM / 64, 32), 256, 0, stream>>>(
        xb, pwT, patch_b, nullptr, h + DM, nullptr, L_LEN, DM, DIN, 1.f, 0);
    posadd_kernel<<<S_LEN, 256, 0, stream>>>(h, coords, pos_emb, cls_tok);

    for (int l = 0; l < 4; ++l) {
        const size_t lDD = (size_t)l * DD;
        const size_t lDF = (size_t)l * DF;
        prep_weights<<<1728, 256, 0, stream>>>(
            wq + lDD, wk + lDD, wv + lDD, wo + lDD, w1 + lDF, w2 + lDF,
            wTdd, w1T, w2T);

        ln_kernel<<<S_LEN, 192, 0, stream>>>(h, t, ln1_g + l * DM, ln1_b + l * DM);
        qkv_kernel<<<dim3(6, 32, 3), 256, 0, stream>>>(
            t, wTdd, wTdd + DD, wTdd + 2 * DD,
            bq + l * DM, bk + l * DM, bv + l * DM, qb, kb, vb);
        lse_init_kernel<<<(5 * S_LEN * NHEAD) / 256, 256, 0, stream>>>(lse);
        attn_kernel<<<744, 256, 0, stream>>>(qb, kb, vb, obuf, lse);
        combine_kernel<<<S_LEN, 192, 0, stream>>>(obuf, lse, t);
        gemm64_kernel<<<dim3(12, 32), 256, 0, stream>>>(
            t, wTdd + 3 * DD, bo + l * DM, h, h, nullptr, S_LEN, DM, DM, 1.f, 0);
        ln_kernel<<<S_LEN, 192, 0, stream>>>(h, t, ln2_g + l * DM, ln2_b + l * DM);
        gemm128_kernel<<<dim3(24, 32), 256, 0, stream>>>(
            t, w1T, b1 + (size_t)l * FFND, nullptr, nullptr, ffn,
            S_LEN, FFND, DM, 1.f, 1);
        gemm64_kernel<<<dim3(12, 32), 256, 0, stream>>>(
            ffn, w2T, b2 + l * DM, h, h, nullptr, S_LEN, DM, FFND, 1.f, 0);
    }
    final_ln_kernel<<<1, 256, 0, stream>>>(h, enc_g, enc_b, norm_g, norm_b, out);
}